// Round 1
// baseline (2675.226 us; speedup 1.0000x reference)
//
#include <hip/hip_runtime.h>
#include <hip/hip_bf16.h>
#include <math.h>

#define SQ 1024       // sequence length
#define CS 768        // channels
#define CZ 128        // z channels
#define DD 32         // head dim
#define NH 24         // heads
#define EPSV 1e-5f

typedef __hip_bfloat16 bf16;

__device__ __forceinline__ float b2f(bf16 x) { return __bfloat162float(x); }
__device__ __forceinline__ bf16 f2b(float x) { return __float2bfloat16(x); }

// ---------------------------------------------------------------- k_adaln
// emb[b][o] = silu(t[b]) @ w_adaln[:,o] + b_adaln[o]   (o < 2304)
__global__ __launch_bounds__(256) void k_adaln(const float* t, const float* w,
                                               const float* bias, float* emb) {
    __shared__ float st[CS];
    int b = blockIdx.y;
    int o = blockIdx.x * 256 + threadIdx.x;
    for (int c = threadIdx.x; c < CS; c += 256) {
        float x = t[b * CS + c];
        st[c] = x / (1.0f + __expf(-x));
    }
    __syncthreads();
    float acc = bias[o];
    for (int c = 0; c < CS; ++c)
        acc += st[c] * w[(size_t)c * (3 * CS) + o];
    emb[(size_t)b * 3 * CS + o] = acc;
}

// ---------------------------------------------------------------- k_bsnorm
// bsn[b,s,c] = LN(bs[b,s,:])[c] * (1+scale[b,c]) + shift[b,c]
__global__ __launch_bounds__(256) void k_bsnorm(const float* bs, const float* emb,
                                                float* bsn) {
    int row = blockIdx.x;              // b*SQ + s
    int b = row >> 10;
    const float* x = bs + (size_t)row * CS;
    float v[3], s1 = 0.f, s2 = 0.f;
    #pragma unroll
    for (int i = 0; i < 3; i++) {
        float f = x[threadIdx.x + i * 256];
        v[i] = f; s1 += f; s2 += f * f;
    }
    __shared__ float red[8];
    for (int off = 32; off; off >>= 1) { s1 += __shfl_down(s1, off); s2 += __shfl_down(s2, off); }
    int wid = threadIdx.x >> 6;
    if ((threadIdx.x & 63) == 0) { red[wid] = s1; red[wid + 4] = s2; }
    __syncthreads();
    s1 = red[0] + red[1] + red[2] + red[3];
    s2 = red[4] + red[5] + red[6] + red[7];
    float mu = s1 * (1.0f / CS);
    float var = s2 * (1.0f / CS) - mu * mu;
    float rs = rsqrtf(var + EPSV);
    const float* sh = emb + (size_t)b * 3 * CS;
    float* o = bsn + (size_t)row * CS;
    #pragma unroll
    for (int i = 0; i < 3; i++) {
        int c = threadIdx.x + i * 256;
        o[c] = (v[i] - mu) * rs * (1.0f + sh[CS + c]) + sh[c];
    }
}

// ---------------------------------------------------------------- k_gemm_qkv
// C[2048 x 768] = A(fp32) @ W(fp32, [k][n] row-major); store to (b,h,s,d) fp32
__global__ __launch_bounds__(256) void k_gemm_qkv(const float* A, const float* W,
                                                  float* out) {
    __shared__ float As[16][68];   // [k][m]
    __shared__ float Bs[16][68];   // [k][n]
    int t = threadIdx.x;
    int m0g = blockIdx.x * 64;
    int n0g = blockIdx.y * 64;
    int mg = t >> 4, ng = t & 15;
    float acc[4][4] = {};
    for (int k0 = 0; k0 < CS; k0 += 16) {
        {   // stage A 64x16
            int kk = t & 15, mm = t >> 4;
            #pragma unroll
            for (int r = 0; r < 4; r++)
                As[kk][mm + r * 16] = A[(size_t)(m0g + mm + r * 16) * CS + k0 + kk];
            // stage W 16x64 (float4)
            int nn = (t & 15) * 4, kb = t >> 4;
            float4 w4 = *(const float4*)&W[(size_t)(k0 + kb) * CS + n0g + nn];
            *(float4*)&Bs[kb][nn] = w4;
        }
        __syncthreads();
        #pragma unroll
        for (int kk = 0; kk < 16; kk++) {
            float4 a4 = *(const float4*)&As[kk][mg * 4];
            float4 b4 = *(const float4*)&Bs[kk][ng * 4];
            float a[4] = {a4.x, a4.y, a4.z, a4.w};
            float bv[4] = {b4.x, b4.y, b4.z, b4.w};
            #pragma unroll
            for (int ii = 0; ii < 4; ii++)
                #pragma unroll
                for (int jj = 0; jj < 4; jj++)
                    acc[ii][jj] += a[ii] * bv[jj];
        }
        __syncthreads();
    }
    #pragma unroll
    for (int ii = 0; ii < 4; ii++) {
        int r = m0g + mg * 4 + ii;
        int b = r >> 10, s = r & 1023;
        #pragma unroll
        for (int jj = 0; jj < 4; jj++) {
            int c = n0g + ng * 4 + jj;
            int h = c >> 5, d = c & 31;
            out[(((size_t)b * NH + h) * SQ + s) * DD + d] = acc[ii][jj];
        }
    }
}

// ---------------------------------------------------------------- k_rms
// in-place RMS over D=32 groups of (b,h,s)
__global__ __launch_bounds__(256) void k_rms(float* x, const float* w) {
    int g = blockIdx.x * 8 + (threadIdx.x >> 5);
    int d = threadIdx.x & 31;
    float* p = x + (size_t)g * DD + d;
    float v = *p;
    float s = v * v;
    for (int off = 16; off; off >>= 1) s += __shfl_xor(s, off, 32);
    float rs = rsqrtf(s * (1.0f / DD) + EPSV);
    *p = v * rs * w[d];
}

// ---------------------------------------------------------------- k_zbias
// zbias[h, i, j] = bf16( sum_c (LN(z[i,j,:])[c]*lnw[c]+lnb[c]) * wz[c,h] + mask )
// Coalesced rewrite: one block = 64 consecutive rows (a CONTIGUOUS 32 KiB chunk
// of z). Stage to LDS with fully-coalesced float4 loads (single physical pass
// over z), then 4 threads per row (32 channels each) compute stats + the 24-head
// matmul; combine partials with 2x shfl_xor. Row stride padded to 132 floats to
// avoid stride-128 LDS bank aliasing on readback.
#define ZROWS 64
#define ZPAD 132
__global__ __launch_bounds__(256) void k_zbias(const float* z, const int* zmask,
                                               const float* wz, const float* lnw,
                                               const float* lnb, bf16* zbias) {
    __shared__ float zt[ZROWS * ZPAD];   // 33 KiB, padded rows
    __shared__ bf16 ot[NH][ZROWS];       // 3 KiB output staging
    int t = threadIdx.x;
    size_t base = (size_t)blockIdx.x * ZROWS;          // first global row
    const float4* src = (const float4*)(z + base * CZ);
    // ---- stage 64 rows x 128 ch, coalesced (2048 float4, 8 per thread)
    #pragma unroll
    for (int it = 0; it < 8; it++) {
        int gi = t + it * 256;        // float4 index in chunk
        int row = gi >> 5, c4 = gi & 31;
        *(float4*)&zt[row * ZPAD + c4 * 4] = src[gi];
    }
    __syncthreads();
    int r = t >> 2, qd = t & 3;       // 4 lanes per row, each owns 32 channels
    const float* rowp = &zt[r * ZPAD + qd * 32];
    // ---- stats (partial over own 32 channels, reduce across 4 lanes)
    float s1 = 0.f, s2 = 0.f;
    #pragma unroll
    for (int i = 0; i < 8; i++) {
        float4 f = *(const float4*)&rowp[i * 4];
        s1 += f.x + f.y + f.z + f.w;
        s2 += f.x * f.x + f.y * f.y + f.z * f.z + f.w * f.w;
    }
    s1 += __shfl_xor(s1, 1); s2 += __shfl_xor(s2, 1);
    s1 += __shfl_xor(s1, 2); s2 += __shfl_xor(s2, 2);
    float mu = s1 * (1.0f / CZ);
    float var = s2 * (1.0f / CZ) - mu * mu;
    float rs = rsqrtf(var + EPSV);
    // ---- matmul into 24 heads (partial over own 32 channels)
    float acc[NH];
    #pragma unroll
    for (int h = 0; h < NH; h++) acc[h] = 0.f;
    #pragma unroll
    for (int i = 0; i < 8; i++) {
        float4 f = *(const float4*)&rowp[i * 4];
        float e[4] = {f.x, f.y, f.z, f.w};
        #pragma unroll
        for (int u = 0; u < 4; u++) {
            int c = qd * 32 + i * 4 + u;
            float zn = (e[u] - mu) * rs * lnw[c] + lnb[c];
            #pragma unroll
            for (int h = 0; h < NH; h++) acc[h] += zn * wz[c * NH + h];
        }
    }
    #pragma unroll
    for (int h = 0; h < NH; h++) {
        acc[h] += __shfl_xor(acc[h], 1);
        acc[h] += __shfl_xor(acc[h], 2);
    }
    float mb = (zmask[base + r] > 0) ? 0.0f : -1.0e9f;
    // lane qd stages heads [qd*6, qd*6+6)
    #pragma unroll
    for (int hh = 0; hh < 6; hh++) {
        int h = qd * 6 + hh;
        ot[h][r] = f2b(acc[h] + mb);
    }
    __syncthreads();
    // ---- write out: 24 heads x 64 rows, 16 B per lane, 128 B contiguous per head
    size_t SS = (size_t)SQ * SQ;
    if (t < 192) {
        int h = t >> 3, l8 = t & 7;
        uint4 val = *(const uint4*)&ot[h][l8 * 8];
        *(uint4*)&zbias[(size_t)h * SS + base + l8 * 8] = val;
    }
}

// ---------------------------------------------------------------- k_attn
// flash attention per (b,h, 64-row q tile). q,k,v fp32 (b,h,s,d).
__global__ __launch_bounds__(256) void k_attn(const float* q, const float* k,
                                              const float* v, const bf16* zbias,
                                              const float* beta, float* attn_out) {
    int qt = blockIdx.x;   // 0..15
    int bh = blockIdx.y;   // 0..47
    int b = bh / NH, h = bh % NH;
    __shared__ float Qt[DD][68];   // [d][i]
    __shared__ float Kt[DD][68];   // [d][j]
    __shared__ float Vt[64][36];   // [j][d]
    __shared__ float Pt[64][68];   // [j][i]
    __shared__ float m_l[64], l_l[64], al_l[64];
    int t = threadIdx.x;
    const float scale = 0.17677669529663687f;   // 1/sqrt(32)
    const float* qb = q + ((size_t)bh * SQ + qt * 64) * DD;
    for (int i = t; i < 64 * DD; i += 256) {
        int r = i / DD, d = i % DD;
        Qt[d][r] = qb[i] * scale;
    }
    if (t < 64) { m_l[t] = -3.0e38f; l_l[t] = 0.f; }
    float O[2][4] = {};
    int ig = t >> 4, jg = t & 15;     // score mapping: rows ig*4.., cols jg*4..
    int ig2 = t >> 3, dg = t & 7;     // PV mapping: rows ig2*2.., d dg*4..
    size_t SS = (size_t)SQ * SQ;
    __syncthreads();
    for (int kt = 0; kt < 16; kt++) {
        const float* kb = k + ((size_t)bh * SQ + kt * 64) * DD;
        const float* vb = v + ((size_t)bh * SQ + kt * 64) * DD;
        for (int i = t; i < 64 * DD; i += 256) {
            int r = i / DD, d = i % DD;
            Kt[d][r] = kb[i];
            Vt[r][d] = vb[i];
        }
        __syncthreads();
        // ---- scores (4x4 per thread) with bias
        float sc[4][4];
        size_t ibase = (size_t)(qt * 64 + ig * 4);
        int jbase = kt * 64 + jg * 4;
        #pragma unroll
        for (int ii = 0; ii < 4; ii++) {
            size_t ro = (ibase + ii) * SQ + jbase;
            union { unsigned long long u; bf16 hh[4]; } zz;
            zz.u = *(const unsigned long long*)&zbias[(size_t)h * SS + ro];
            float4 bb = *(const float4*)&beta[(size_t)b * SS + ro];
            sc[ii][0] = b2f(zz.hh[0]) + bb.x;
            sc[ii][1] = b2f(zz.hh[1]) + bb.y;
            sc[ii][2] = b2f(zz.hh[2]) + bb.z;
            sc[ii][3] = b2f(zz.hh[3]) + bb.w;
        }
        #pragma unroll
        for (int d = 0; d < DD; d++) {
            float4 qa4 = *(const float4*)&Qt[d][ig * 4];
            float4 ka4 = *(const float4*)&Kt[d][jg * 4];
            float qa[4] = {qa4.x, qa4.y, qa4.z, qa4.w};
            float ka[4] = {ka4.x, ka4.y, ka4.z, ka4.w};
            #pragma unroll
            for (int ii = 0; ii < 4; ii++)
                #pragma unroll
                for (int jj = 0; jj < 4; jj++)
                    sc[ii][jj] += qa[ii] * ka[jj];
        }
        // ---- online softmax (rows owned by 16 consecutive lanes)
        #pragma unroll
        for (int ii = 0; ii < 4; ii++) {
            int row = ig * 4 + ii;
            float mx = sc[ii][0];
            #pragma unroll
            for (int jj = 1; jj < 4; jj++) mx = fmaxf(mx, sc[ii][jj]);
            for (int off = 1; off < 16; off <<= 1) mx = fmaxf(mx, __shfl_xor(mx, off, 64));
            float mo = m_l[row];
            float mn = fmaxf(mo, mx);
            float al = __expf(mo - mn);
            float ps = 0.f;
            #pragma unroll
            for (int jj = 0; jj < 4; jj++) {
                sc[ii][jj] = __expf(sc[ii][jj] - mn);
                ps += sc[ii][jj];
            }
            for (int off = 1; off < 16; off <<= 1) ps += __shfl_xor(ps, off, 64);
            if (jg == 0) {
                m_l[row] = mn;
                al_l[row] = al;
                l_l[row] = l_l[row] * al + ps;
            }
        }
        // write P transposed [j][i]
        #pragma unroll
        for (int jj = 0; jj < 4; jj++) {
            float4 pv = make_float4(sc[0][jj], sc[1][jj], sc[2][jj], sc[3][jj]);
            *(float4*)&Pt[jg * 4 + jj][ig * 4] = pv;
        }
        __syncthreads();
        // ---- PV accumulate (2 rows x 4 d per thread)
        float a0 = al_l[ig2 * 2], a1 = al_l[ig2 * 2 + 1];
        #pragma unroll
        for (int dd = 0; dd < 4; dd++) { O[0][dd] *= a0; O[1][dd] *= a1; }
        for (int j = 0; j < 64; j++) {
            float p0 = Pt[j][ig2 * 2], p1 = Pt[j][ig2 * 2 + 1];
            float4 vv4 = *(const float4*)&Vt[j][dg * 4];
            float vv[4] = {vv4.x, vv4.y, vv4.z, vv4.w};
            #pragma unroll
            for (int dd = 0; dd < 4; dd++) { O[0][dd] += p0 * vv[dd]; O[1][dd] += p1 * vv[dd]; }
        }
        __syncthreads();
    }
    float r0 = 1.0f / l_l[ig2 * 2];
    float r1 = 1.0f / l_l[ig2 * 2 + 1];
    size_t base = ((size_t)b * SQ + qt * 64 + ig2 * 2) * CS + h * DD + dg * 4;
    float* o0 = attn_out + base;
    *(float4*)o0 = make_float4(O[0][0] * r0, O[0][1] * r0, O[0][2] * r0, O[0][3] * r0);
    *(float4*)(o0 + CS) = make_float4(O[1][0] * r1, O[1][1] * r1, O[1][2] * r1, O[1][3] * r1);
}

// ---------------------------------------------------------------- k_gemm_out
// out[r,c] = (A @ w_o + b_o[c]) * gate[b,c]   (fp32 out)
__global__ __launch_bounds__(256) void k_gemm_out(const float* A, const float* W,
                                                  const float* b_o, const float* emb,
                                                  float* out) {
    __shared__ float As[16][68];
    __shared__ float Bs[16][68];
    int t = threadIdx.x;
    int m0g = blockIdx.x * 64;
    int n0g = blockIdx.y * 64;
    int mg = t >> 4, ng = t & 15;
    float acc[4][4] = {};
    for (int k0 = 0; k0 < CS; k0 += 16) {
        {
            int kk = t & 15, mm = t >> 4;
            #pragma unroll
            for (int r = 0; r < 4; r++)
                As[kk][mm + r * 16] = A[(size_t)(m0g + mm + r * 16) * CS + k0 + kk];
            int nn = (t & 15) * 4, kb = t >> 4;
            float4 w4 = *(const float4*)&W[(size_t)(k0 + kb) * CS + n0g + nn];
            *(float4*)&Bs[kb][nn] = w4;
        }
        __syncthreads();
        #pragma unroll
        for (int kk = 0; kk < 16; kk++) {
            float4 a4 = *(const float4*)&As[kk][mg * 4];
            float4 b4 = *(const float4*)&Bs[kk][ng * 4];
            float a[4] = {a4.x, a4.y, a4.z, a4.w};
            float bv[4] = {b4.x, b4.y, b4.z, b4.w};
            #pragma unroll
            for (int ii = 0; ii < 4; ii++)
                #pragma unroll
                for (int jj = 0; jj < 4; jj++)
                    acc[ii][jj] += a[ii] * bv[jj];
        }
        __syncthreads();
    }
    #pragma unroll
    for (int ii = 0; ii < 4; ii++) {
        int r = m0g + mg * 4 + ii;
        int b = r >> 10;
        int c0 = n0g + ng * 4;
        const float* gt = emb + (size_t)b * 3 * CS + 2 * CS;
        float4 o4;
        o4.x = (acc[ii][0] + b_o[c0 + 0]) * gt[c0 + 0];
        o4.y = (acc[ii][1] + b_o[c0 + 1]) * gt[c0 + 1];
        o4.z = (acc[ii][2] + b_o[c0 + 2]) * gt[c0 + 2];
        o4.w = (acc[ii][3] + b_o[c0 + 3]) * gt[c0 + 3];
        *(float4*)&out[(size_t)r * CS + c0] = o4;
    }
}

// ---------------------------------------------------------------- launch
extern "C" void kernel_launch(void* const* d_in, const int* in_sizes, int n_in,
                              void* d_out, int out_size, void* d_ws, size_t ws_size,
                              hipStream_t stream) {
    const float* bs      = (const float*)d_in[0];
    const float* z       = (const float*)d_in[1];
    const float* t       = (const float*)d_in[2];
    const float* beta    = (const float*)d_in[3];
    const int*   z_mask  = (const int*)d_in[4];
    const float* w_adaln = (const float*)d_in[5];
    const float* b_adaln = (const float*)d_in[6];
    const float* ln_z_w  = (const float*)d_in[7];
    const float* ln_z_b  = (const float*)d_in[8];
    const float* w_q     = (const float*)d_in[9];
    const float* w_k     = (const float*)d_in[10];
    const float* w_v     = (const float*)d_in[11];
    const float* w_z     = (const float*)d_in[12];
    const float* rms_q_w = (const float*)d_in[13];
    const float* rms_k_w = (const float*)d_in[14];
    const float* w_o     = (const float*)d_in[15];
    const float* b_o     = (const float*)d_in[16];
    float* out = (float*)d_out;

    char* ws = (char*)d_ws;
    const size_t SZ_QKV = (size_t)2 * SQ * CS * 4;   // 6291456
    float* emb   = (float*)(ws);                      // 2*2304*4 = 18432
    float* bsn   = (float*)(ws + 32768);
    float* qbuf  = (float*)(ws + 32768 + SZ_QKV);
    float* kbuf  = (float*)(ws + 32768 + 2 * SZ_QKV);
    float* vbuf  = (float*)(ws + 32768 + 3 * SZ_QKV);
    float* attn  = (float*)(ws + 32768 + 4 * SZ_QKV);
    bf16*  zbias = (bf16*)(ws + 32768 + 5 * SZ_QKV);  // 24*1024*1024*2 = 50331648

    k_adaln<<<dim3(9, 2), 256, 0, stream>>>(t, w_adaln, b_adaln, emb);
    k_bsnorm<<<2048, 256, 0, stream>>>(bs, emb, bsn);
    k_gemm_qkv<<<dim3(32, 12), 256, 0, stream>>>(bsn, w_q, qbuf);
    k_gemm_qkv<<<dim3(32, 12), 256, 0, stream>>>(bsn, w_k, kbuf);
    k_gemm_qkv<<<dim3(32, 12), 256, 0, stream>>>(bsn, w_v, vbuf);
    k_rms<<<6144, 256, 0, stream>>>(qbuf, rms_q_w);
    k_rms<<<6144, 256, 0, stream>>>(kbuf, rms_k_w);
    k_zbias<<<16384, 256, 0, stream>>>(z, z_mask, w_z, ln_z_w, ln_z_b, zbias);
    k_attn<<<dim3(16, 48), 256, 0, stream>>>(qbuf, kbuf, vbuf, zbias, beta, attn);
    k_gemm_out<<<dim3(32, 12), 256, 0, stream>>>(attn, w_o, b_o, emb, out);
}

// Round 2
// 1385.271 us; speedup vs baseline: 1.9312x; 1.9312x over previous
//
#include <hip/hip_runtime.h>
#include <hip/hip_bf16.h>
#include <math.h>

#define SQ 1024       // sequence length
#define CS 768        // channels
#define CZ 128        // z channels
#define DD 32         // head dim
#define NH 24         // heads
#define EPSV 1e-5f

typedef __hip_bfloat16 bf16;

__device__ __forceinline__ float b2f(bf16 x) { return __bfloat162float(x); }
__device__ __forceinline__ bf16 f2b(float x) { return __float2bfloat16(x); }

// ---------------------------------------------------------------- k_adaln
// emb[b][o] = silu(t[b]) @ w_adaln[:,o] + b_adaln[o]   (o < 2304)
__global__ __launch_bounds__(256) void k_adaln(const float* t, const float* w,
                                               const float* bias, float* emb) {
    __shared__ float st[CS];
    int b = blockIdx.y;
    int o = blockIdx.x * 256 + threadIdx.x;
    for (int c = threadIdx.x; c < CS; c += 256) {
        float x = t[b * CS + c];
        st[c] = x / (1.0f + __expf(-x));
    }
    __syncthreads();
    float acc = bias[o];
    for (int c = 0; c < CS; ++c)
        acc += st[c] * w[(size_t)c * (3 * CS) + o];
    emb[(size_t)b * 3 * CS + o] = acc;
}

// ---------------------------------------------------------------- k_bsnorm
// bsn[b,s,c] = LN(bs[b,s,:])[c] * (1+scale[b,c]) + shift[b,c]
__global__ __launch_bounds__(256) void k_bsnorm(const float* bs, const float* emb,
                                                float* bsn) {
    int row = blockIdx.x;              // b*SQ + s
    int b = row >> 10;
    const float* x = bs + (size_t)row * CS;
    float v[3], s1 = 0.f, s2 = 0.f;
    #pragma unroll
    for (int i = 0; i < 3; i++) {
        float f = x[threadIdx.x + i * 256];
        v[i] = f; s1 += f; s2 += f * f;
    }
    __shared__ float red[8];
    for (int off = 32; off; off >>= 1) { s1 += __shfl_down(s1, off); s2 += __shfl_down(s2, off); }
    int wid = threadIdx.x >> 6;
    if ((threadIdx.x & 63) == 0) { red[wid] = s1; red[wid + 4] = s2; }
    __syncthreads();
    s1 = red[0] + red[1] + red[2] + red[3];
    s2 = red[4] + red[5] + red[6] + red[7];
    float mu = s1 * (1.0f / CS);
    float var = s2 * (1.0f / CS) - mu * mu;
    float rs = rsqrtf(var + EPSV);
    const float* sh = emb + (size_t)b * 3 * CS;
    float* o = bsn + (size_t)row * CS;
    #pragma unroll
    for (int i = 0; i < 3; i++) {
        int c = threadIdx.x + i * 256;
        o[c] = (v[i] - mu) * rs * (1.0f + sh[CS + c]) + sh[c];
    }
}

// ---------------------------------------------------------------- k_gemm_qkv
// C[2048 x 768] = A(fp32) @ W(fp32, [k][n] row-major); store to (b,h,s,d) fp32
__global__ __launch_bounds__(256) void k_gemm_qkv(const float* A, const float* W,
                                                  float* out) {
    __shared__ float As[16][68];   // [k][m]
    __shared__ float Bs[16][68];   // [k][n]
    int t = threadIdx.x;
    int m0g = blockIdx.x * 64;
    int n0g = blockIdx.y * 64;
    int mg = t >> 4, ng = t & 15;
    float acc[4][4] = {};
    for (int k0 = 0; k0 < CS; k0 += 16) {
        {   // stage A 64x16
            int kk = t & 15, mm = t >> 4;
            #pragma unroll
            for (int r = 0; r < 4; r++)
                As[kk][mm + r * 16] = A[(size_t)(m0g + mm + r * 16) * CS + k0 + kk];
            // stage W 16x64 (float4)
            int nn = (t & 15) * 4, kb = t >> 4;
            float4 w4 = *(const float4*)&W[(size_t)(k0 + kb) * CS + n0g + nn];
            *(float4*)&Bs[kb][nn] = w4;
        }
        __syncthreads();
        #pragma unroll
        for (int kk = 0; kk < 16; kk++) {
            float4 a4 = *(const float4*)&As[kk][mg * 4];
            float4 b4 = *(const float4*)&Bs[kk][ng * 4];
            float a[4] = {a4.x, a4.y, a4.z, a4.w};
            float bv[4] = {b4.x, b4.y, b4.z, b4.w};
            #pragma unroll
            for (int ii = 0; ii < 4; ii++)
                #pragma unroll
                for (int jj = 0; jj < 4; jj++)
                    acc[ii][jj] += a[ii] * bv[jj];
        }
        __syncthreads();
    }
    #pragma unroll
    for (int ii = 0; ii < 4; ii++) {
        int r = m0g + mg * 4 + ii;
        int b = r >> 10, s = r & 1023;
        #pragma unroll
        for (int jj = 0; jj < 4; jj++) {
            int c = n0g + ng * 4 + jj;
            int h = c >> 5, d = c & 31;
            out[(((size_t)b * NH + h) * SQ + s) * DD + d] = acc[ii][jj];
        }
    }
}

// ---------------------------------------------------------------- k_rms
// in-place RMS over D=32 groups of (b,h,s)
__global__ __launch_bounds__(256) void k_rms(float* x, const float* w) {
    int g = blockIdx.x * 8 + (threadIdx.x >> 5);
    int d = threadIdx.x & 31;
    float* p = x + (size_t)g * DD + d;
    float v = *p;
    float s = v * v;
    for (int off = 16; off; off >>= 1) s += __shfl_xor(s, off, 32);
    float rs = rsqrtf(s * (1.0f / DD) + EPSV);
    *p = v * rs * w[d];
}

// ---------------------------------------------------------------- k_uv
// U[h] = sum_c lnw[c]*wz[c,h];  V[h] = sum_c lnb[c]*wz[c,h]  (48 floats)
__global__ __launch_bounds__(64) void k_uv(const float* wz, const float* lnw,
                                           const float* lnb, float* uv) {
    int t = threadIdx.x;
    if (t < 2 * NH) {
        int h = t % NH;
        const float* s = (t < NH) ? lnw : lnb;
        float a = 0.f;
        for (int c = 0; c < CZ; ++c) a += s[c] * wz[c * NH + h];
        uv[t] = a;
    }
}

// ---------------------------------------------------------------- k_zbias
// zbias[h,i,j] = bf16( rs*P[h] - mu*rs*U[h] + V[h] + maskbias ),
//   P[h] = sum_c z[c]*lnw[c]*wz[c,h]
// Block = 64 consecutive rows (contiguous 32 KiB of z), staged coalesced into
// LDS with XOR swizzle (c ^= 4*(row>>3); row stride 132 floats) so staging
// writes, b128 row reads are bank-balanced. Wave w owns channel quarter
// [w*32,w*32+32) for ALL 64 rows (lane=row) -> c is WAVE-UNIFORM -> wz/lnw are
// scalar s_loads, inner loop is pure reg FMA. One LDS reduction (reusing the
// z-tile memory, stride 27 coprime with 32) combines the 4 partials.
#define ZROWS 64
#define ZSTRIDE 132
__global__ __launch_bounds__(256) void k_zbias(const float* z, const int* zmask,
                                               const float* wz, const float* lnw,
                                               const float* lnb, const float* uv,
                                               bf16* zbias) {
    __shared__ float zt[ZROWS * ZSTRIDE];   // 33792 B; reused for partials
    __shared__ bf16 ot[NH][ZROWS];          // 3 KiB output staging
    int t = threadIdx.x;
    size_t base = (size_t)blockIdx.x * ZROWS;
    const float4* src = (const float4*)(z + base * CZ);
    // ---- stage 64x128, coalesced float4, swizzled LDS placement
    #pragma unroll
    for (int it = 0; it < 8; it++) {
        int gi = t + it * 256;                 // float4 index in 32 KiB chunk
        int row = gi >> 5, c4 = gi & 31;
        int cs = (c4 * 4) ^ ((row >> 3) << 2); // channel-group swizzle
        *(float4*)&zt[row * ZSTRIDE + cs] = src[gi];
    }
    __syncthreads();
    int lane = t & 63;
    int qd = __builtin_amdgcn_readfirstlane(t >> 6);   // wave id = channel quarter
    int sw = (lane >> 3) << 2;
    float acc[NH];
    #pragma unroll
    for (int h = 0; h < NH; h++) acc[h] = 0.f;
    float s1 = 0.f, s2 = 0.f;
    #pragma unroll
    for (int i = 0; i < 8; i++) {
        int c0 = qd * 32 + i * 4;              // wave-uniform channel base
        float4 zv = *(const float4*)&zt[lane * ZSTRIDE + (c0 ^ sw)];
        float e[4] = {zv.x, zv.y, zv.z, zv.w};
        #pragma unroll
        for (int u = 0; u < 4; u++) {
            int c = c0 + u;                    // wave-uniform -> s_loads below
            float zval = e[u];
            s1 += zval;
            s2 = fmaf(zval, zval, s2);
            float tc = zval * lnw[c];
            #pragma unroll
            for (int h = 0; h < NH; h++)
                acc[h] = fmaf(tc, wz[c * NH + h], acc[h]);
        }
    }
    __syncthreads();   // all waves done reading zt -> safe to reuse as partials
    // partial layout: zt[q*1728 + r*27 + j], j0=s1 j1=s2 j2..j25=acc (27 coprime 32)
    {
        float* pp = zt + qd * (ZROWS * 27) + lane * 27;
        pp[0] = s1; pp[1] = s2;
        #pragma unroll
        for (int h = 0; h < NH; h++) pp[2 + h] = acc[h];
    }
    __syncthreads();
    // ---- final combine: thread t -> row r = t&63, heads hb..hb+5
    int r = lane;
    int hb = qd * 6;
    float fs1 = 0.f, fs2 = 0.f;
    float fa[6] = {};
    #pragma unroll
    for (int q = 0; q < 4; q++) {
        const float* p = zt + q * (ZROWS * 27) + r * 27;
        fs1 += p[0]; fs2 += p[1];
        #pragma unroll
        for (int j = 0; j < 6; j++) fa[j] += p[2 + hb + j];
    }
    float mu = fs1 * (1.0f / CZ);
    float var = fs2 * (1.0f / CZ) - mu * mu;
    float rs = rsqrtf(var + EPSV);
    float mb = (zmask[base + r] > 0) ? 0.0f : -1.0e9f;
    #pragma unroll
    for (int j = 0; j < 6; j++) {
        int h = hb + j;                        // hb wave-uniform -> uv via s_load
        float val = rs * fa[j] - mu * rs * uv[h] + uv[NH + h] + mb;
        ot[h][r] = f2b(val);
    }
    __syncthreads();
    // ---- write out: 24 heads x 64 rows, 16 B per lane, contiguous per head
    size_t SS = (size_t)SQ * SQ;
    if (t < 192) {
        int h = t >> 3, l8 = t & 7;
        uint4 val = *(const uint4*)&ot[h][l8 * 8];
        *(uint4*)&zbias[(size_t)h * SS + base + l8 * 8] = val;
    }
}

// ---------------------------------------------------------------- k_attn
// flash attention per (b,h, 64-row q tile). q,k,v fp32 (b,h,s,d).
__global__ __launch_bounds__(256) void k_attn(const float* q, const float* k,
                                              const float* v, const bf16* zbias,
                                              const float* beta, float* attn_out) {
    int qt = blockIdx.x;   // 0..15
    int bh = blockIdx.y;   // 0..47
    int b = bh / NH, h = bh % NH;
    __shared__ float Qt[DD][68];   // [d][i]
    __shared__ float Kt[DD][68];   // [d][j]
    __shared__ float Vt[64][36];   // [j][d]
    __shared__ float Pt[64][68];   // [j][i]
    __shared__ float m_l[64], l_l[64], al_l[64];
    int t = threadIdx.x;
    const float scale = 0.17677669529663687f;   // 1/sqrt(32)
    const float* qb = q + ((size_t)bh * SQ + qt * 64) * DD;
    for (int i = t; i < 64 * DD; i += 256) {
        int r = i / DD, d = i % DD;
        Qt[d][r] = qb[i] * scale;
    }
    if (t < 64) { m_l[t] = -3.0e38f; l_l[t] = 0.f; }
    float O[2][4] = {};
    int ig = t >> 4, jg = t & 15;     // score mapping: rows ig*4.., cols jg*4..
    int ig2 = t >> 3, dg = t & 7;     // PV mapping: rows ig2*2.., d dg*4..
    size_t SS = (size_t)SQ * SQ;
    __syncthreads();
    for (int kt = 0; kt < 16; kt++) {
        const float* kb = k + ((size_t)bh * SQ + kt * 64) * DD;
        const float* vb = v + ((size_t)bh * SQ + kt * 64) * DD;
        for (int i = t; i < 64 * DD; i += 256) {
            int r = i / DD, d = i % DD;
            Kt[d][r] = kb[i];
            Vt[r][d] = vb[i];
        }
        __syncthreads();
        // ---- scores (4x4 per thread) with bias
        float sc[4][4];
        size_t ibase = (size_t)(qt * 64 + ig * 4);
        int jbase = kt * 64 + jg * 4;
        #pragma unroll
        for (int ii = 0; ii < 4; ii++) {
            size_t ro = (ibase + ii) * SQ + jbase;
            union { unsigned long long u; bf16 hh[4]; } zz;
            zz.u = *(const unsigned long long*)&zbias[(size_t)h * SS + ro];
            float4 bb = *(const float4*)&beta[(size_t)b * SS + ro];
            sc[ii][0] = b2f(zz.hh[0]) + bb.x;
            sc[ii][1] = b2f(zz.hh[1]) + bb.y;
            sc[ii][2] = b2f(zz.hh[2]) + bb.z;
            sc[ii][3] = b2f(zz.hh[3]) + bb.w;
        }
        #pragma unroll
        for (int d = 0; d < DD; d++) {
            float4 qa4 = *(const float4*)&Qt[d][ig * 4];
            float4 ka4 = *(const float4*)&Kt[d][jg * 4];
            float qa[4] = {qa4.x, qa4.y, qa4.z, qa4.w};
            float ka[4] = {ka4.x, ka4.y, ka4.z, ka4.w};
            #pragma unroll
            for (int ii = 0; ii < 4; ii++)
                #pragma unroll
                for (int jj = 0; jj < 4; jj++)
                    sc[ii][jj] += qa[ii] * ka[jj];
        }
        // ---- online softmax (rows owned by 16 consecutive lanes)
        #pragma unroll
        for (int ii = 0; ii < 4; ii++) {
            int row = ig * 4 + ii;
            float mx = sc[ii][0];
            #pragma unroll
            for (int jj = 1; jj < 4; jj++) mx = fmaxf(mx, sc[ii][jj]);
            for (int off = 1; off < 16; off <<= 1) mx = fmaxf(mx, __shfl_xor(mx, off, 64));
            float mo = m_l[row];
            float mn = fmaxf(mo, mx);
            float al = __expf(mo - mn);
            float ps = 0.f;
            #pragma unroll
            for (int jj = 0; jj < 4; jj++) {
                sc[ii][jj] = __expf(sc[ii][jj] - mn);
                ps += sc[ii][jj];
            }
            for (int off = 1; off < 16; off <<= 1) ps += __shfl_xor(ps, off, 64);
            if (jg == 0) {
                m_l[row] = mn;
                al_l[row] = al;
                l_l[row] = l_l[row] * al + ps;
            }
        }
        // write P transposed [j][i]
        #pragma unroll
        for (int jj = 0; jj < 4; jj++) {
            float4 pv = make_float4(sc[0][jj], sc[1][jj], sc[2][jj], sc[3][jj]);
            *(float4*)&Pt[jg * 4 + jj][ig * 4] = pv;
        }
        __syncthreads();
        // ---- PV accumulate (2 rows x 4 d per thread)
        float a0 = al_l[ig2 * 2], a1 = al_l[ig2 * 2 + 1];
        #pragma unroll
        for (int dd = 0; dd < 4; dd++) { O[0][dd] *= a0; O[1][dd] *= a1; }
        for (int j = 0; j < 64; j++) {
            float p0 = Pt[j][ig2 * 2], p1 = Pt[j][ig2 * 2 + 1];
            float4 vv4 = *(const float4*)&Vt[j][dg * 4];
            float vv[4] = {vv4.x, vv4.y, vv4.z, vv4.w};
            #pragma unroll
            for (int dd = 0; dd < 4; dd++) { O[0][dd] += p0 * vv[dd]; O[1][dd] += p1 * vv[dd]; }
        }
        __syncthreads();
    }
    float r0 = 1.0f / l_l[ig2 * 2];
    float r1 = 1.0f / l_l[ig2 * 2 + 1];
    size_t base = ((size_t)b * SQ + qt * 64 + ig2 * 2) * CS + h * DD + dg * 4;
    float* o0 = attn_out + base;
    *(float4*)o0 = make_float4(O[0][0] * r0, O[0][1] * r0, O[0][2] * r0, O[0][3] * r0);
    *(float4*)(o0 + CS) = make_float4(O[1][0] * r1, O[1][1] * r1, O[1][2] * r1, O[1][3] * r1);
}

// ---------------------------------------------------------------- k_gemm_out
// out[r,c] = (A @ w_o + b_o[c]) * gate[b,c]   (fp32 out)
__global__ __launch_bounds__(256) void k_gemm_out(const float* A, const float* W,
                                                  const float* b_o, const float* emb,
                                                  float* out) {
    __shared__ float As[16][68];
    __shared__ float Bs[16][68];
    int t = threadIdx.x;
    int m0g = blockIdx.x * 64;
    int n0g = blockIdx.y * 64;
    int mg = t >> 4, ng = t & 15;
    float acc[4][4] = {};
    for (int k0 = 0; k0 < CS; k0 += 16) {
        {
            int kk = t & 15, mm = t >> 4;
            #pragma unroll
            for (int r = 0; r < 4; r++)
                As[kk][mm + r * 16] = A[(size_t)(m0g + mm + r * 16) * CS + k0 + kk];
            int nn = (t & 15) * 4, kb = t >> 4;
            float4 w4 = *(const float4*)&W[(size_t)(k0 + kb) * CS + n0g + nn];
            *(float4*)&Bs[kb][nn] = w4;
        }
        __syncthreads();
        #pragma unroll
        for (int kk = 0; kk < 16; kk++) {
            float4 a4 = *(const float4*)&As[kk][mg * 4];
            float4 b4 = *(const float4*)&Bs[kk][ng * 4];
            float a[4] = {a4.x, a4.y, a4.z, a4.w};
            float bv[4] = {b4.x, b4.y, b4.z, b4.w};
            #pragma unroll
            for (int ii = 0; ii < 4; ii++)
                #pragma unroll
                for (int jj = 0; jj < 4; jj++)
                    acc[ii][jj] += a[ii] * bv[jj];
        }
        __syncthreads();
    }
    #pragma unroll
    for (int ii = 0; ii < 4; ii++) {
        int r = m0g + mg * 4 + ii;
        int b = r >> 10;
        int c0 = n0g + ng * 4;
        const float* gt = emb + (size_t)b * 3 * CS + 2 * CS;
        float4 o4;
        o4.x = (acc[ii][0] + b_o[c0 + 0]) * gt[c0 + 0];
        o4.y = (acc[ii][1] + b_o[c0 + 1]) * gt[c0 + 1];
        o4.z = (acc[ii][2] + b_o[c0 + 2]) * gt[c0 + 2];
        o4.w = (acc[ii][3] + b_o[c0 + 3]) * gt[c0 + 3];
        *(float4*)&out[(size_t)r * CS + c0] = o4;
    }
}

// ---------------------------------------------------------------- launch
extern "C" void kernel_launch(void* const* d_in, const int* in_sizes, int n_in,
                              void* d_out, int out_size, void* d_ws, size_t ws_size,
                              hipStream_t stream) {
    const float* bs      = (const float*)d_in[0];
    const float* z       = (const float*)d_in[1];
    const float* t       = (const float*)d_in[2];
    const float* beta    = (const float*)d_in[3];
    const int*   z_mask  = (const int*)d_in[4];
    const float* w_adaln = (const float*)d_in[5];
    const float* b_adaln = (const float*)d_in[6];
    const float* ln_z_w  = (const float*)d_in[7];
    const float* ln_z_b  = (const float*)d_in[8];
    const float* w_q     = (const float*)d_in[9];
    const float* w_k     = (const float*)d_in[10];
    const float* w_v     = (const float*)d_in[11];
    const float* w_z     = (const float*)d_in[12];
    const float* rms_q_w = (const float*)d_in[13];
    const float* rms_k_w = (const float*)d_in[14];
    const float* w_o     = (const float*)d_in[15];
    const float* b_o     = (const float*)d_in[16];
    float* out = (float*)d_out;

    char* ws = (char*)d_ws;
    const size_t SZ_QKV = (size_t)2 * SQ * CS * 4;   // 6291456
    float* emb   = (float*)(ws);                      // 2*2304*4 = 18432
    float* bsn   = (float*)(ws + 32768);
    float* qbuf  = (float*)(ws + 32768 + SZ_QKV);
    float* kbuf  = (float*)(ws + 32768 + 2 * SZ_QKV);
    float* vbuf  = (float*)(ws + 32768 + 3 * SZ_QKV);
    float* attn  = (float*)(ws + 32768 + 4 * SZ_QKV);
    bf16*  zbias = (bf16*)(ws + 32768 + 5 * SZ_QKV);  // 24*1024*1024*2 = 50331648
    float* uv    = (float*)(ws + 32768 + 5 * SZ_QKV + 50331648);  // 48 floats

    k_adaln<<<dim3(9, 2), 256, 0, stream>>>(t, w_adaln, b_adaln, emb);
    k_uv<<<1, 64, 0, stream>>>(w_z, ln_z_w, ln_z_b, uv);
    k_bsnorm<<<2048, 256, 0, stream>>>(bs, emb, bsn);
    k_gemm_qkv<<<dim3(32, 12), 256, 0, stream>>>(bsn, w_q, qbuf);
    k_gemm_qkv<<<dim3(32, 12), 256, 0, stream>>>(bsn, w_k, kbuf);
    k_gemm_qkv<<<dim3(32, 12), 256, 0, stream>>>(bsn, w_v, vbuf);
    k_rms<<<6144, 256, 0, stream>>>(qbuf, rms_q_w);
    k_rms<<<6144, 256, 0, stream>>>(kbuf, rms_k_w);
    k_zbias<<<16384, 256, 0, stream>>>(z, z_mask, w_z, ln_z_w, ln_z_b, uv, zbias);
    k_attn<<<dim3(16, 48), 256, 0, stream>>>(qbuf, kbuf, vbuf, zbias, beta, attn);
    k_gemm_out<<<dim3(32, 12), 256, 0, stream>>>(attn, w_o, b_o, emb, out);
}

// Round 3
// 1107.986 us; speedup vs baseline: 2.4145x; 1.2503x over previous
//
#include <hip/hip_runtime.h>
#include <hip/hip_bf16.h>
#include <math.h>

#define SQ 1024       // sequence length
#define CS 768        // channels
#define CZ 128        // z channels
#define DD 32         // head dim
#define NH 24         // heads
#define EPSV 1e-5f

typedef __hip_bfloat16 bf16;
typedef _Float16 f16;
typedef _Float16 f16x8 __attribute__((ext_vector_type(8)));
typedef float f32x4 __attribute__((ext_vector_type(4)));

__device__ __forceinline__ float b2f(bf16 x) { return __bfloat162float(x); }
__device__ __forceinline__ bf16 f2b(float x) { return __float2bfloat16(x); }

// ---------------------------------------------------------------- k_adaln
// emb[b][o] = silu(t[b]) @ w_adaln[:,o] + b_adaln[o]   (o < 2304)
__global__ __launch_bounds__(256) void k_adaln(const float* t, const float* w,
                                               const float* bias, float* emb) {
    __shared__ float st[CS];
    int b = blockIdx.y;
    int o = blockIdx.x * 256 + threadIdx.x;
    for (int c = threadIdx.x; c < CS; c += 256) {
        float x = t[b * CS + c];
        st[c] = x / (1.0f + __expf(-x));
    }
    __syncthreads();
    float acc = bias[o];
    for (int c = 0; c < CS; ++c)
        acc += st[c] * w[(size_t)c * (3 * CS) + o];
    emb[(size_t)b * 3 * CS + o] = acc;
}

// ---------------------------------------------------------------- k_bsnorm
// bsn[b,s,c] = LN(bs[b,s,:])[c] * (1+scale[b,c]) + shift[b,c]
__global__ __launch_bounds__(256) void k_bsnorm(const float* bs, const float* emb,
                                                float* bsn) {
    int row = blockIdx.x;              // b*SQ + s
    int b = row >> 10;
    const float* x = bs + (size_t)row * CS;
    float v[3], s1 = 0.f, s2 = 0.f;
    #pragma unroll
    for (int i = 0; i < 3; i++) {
        float f = x[threadIdx.x + i * 256];
        v[i] = f; s1 += f; s2 += f * f;
    }
    __shared__ float red[8];
    for (int off = 32; off; off >>= 1) { s1 += __shfl_down(s1, off); s2 += __shfl_down(s2, off); }
    int wid = threadIdx.x >> 6;
    if ((threadIdx.x & 63) == 0) { red[wid] = s1; red[wid + 4] = s2; }
    __syncthreads();
    s1 = red[0] + red[1] + red[2] + red[3];
    s2 = red[4] + red[5] + red[6] + red[7];
    float mu = s1 * (1.0f / CS);
    float var = s2 * (1.0f / CS) - mu * mu;
    float rs = rsqrtf(var + EPSV);
    const float* sh = emb + (size_t)b * 3 * CS;
    float* o = bsn + (size_t)row * CS;
    #pragma unroll
    for (int i = 0; i < 3; i++) {
        int c = threadIdx.x + i * 256;
        o[c] = (v[i] - mu) * rs * (1.0f + sh[CS + c]) + sh[c];
    }
}

// ---------------------------------------------------------------- k_gemm_qkv
// C[2048 x 768] = A(fp32) @ W(fp32, [k][n] row-major); store to (b,h,s,d) fp32
__global__ __launch_bounds__(256) void k_gemm_qkv(const float* A, const float* W,
                                                  float* out) {
    __shared__ float As[16][68];   // [k][m]
    __shared__ float Bs[16][68];   // [k][n]
    int t = threadIdx.x;
    int m0g = blockIdx.x * 64;
    int n0g = blockIdx.y * 64;
    int mg = t >> 4, ng = t & 15;
    float acc[4][4] = {};
    for (int k0 = 0; k0 < CS; k0 += 16) {
        {   // stage A 64x16
            int kk = t & 15, mm = t >> 4;
            #pragma unroll
            for (int r = 0; r < 4; r++)
                As[kk][mm + r * 16] = A[(size_t)(m0g + mm + r * 16) * CS + k0 + kk];
            // stage W 16x64 (float4)
            int nn = (t & 15) * 4, kb = t >> 4;
            float4 w4 = *(const float4*)&W[(size_t)(k0 + kb) * CS + n0g + nn];
            *(float4*)&Bs[kb][nn] = w4;
        }
        __syncthreads();
        #pragma unroll
        for (int kk = 0; kk < 16; kk++) {
            float4 a4 = *(const float4*)&As[kk][mg * 4];
            float4 b4 = *(const float4*)&Bs[kk][ng * 4];
            float a[4] = {a4.x, a4.y, a4.z, a4.w};
            float bv[4] = {b4.x, b4.y, b4.z, b4.w};
            #pragma unroll
            for (int ii = 0; ii < 4; ii++)
                #pragma unroll
                for (int jj = 0; jj < 4; jj++)
                    acc[ii][jj] += a[ii] * bv[jj];
        }
        __syncthreads();
    }
    #pragma unroll
    for (int ii = 0; ii < 4; ii++) {
        int r = m0g + mg * 4 + ii;
        int b = r >> 10, s = r & 1023;
        #pragma unroll
        for (int jj = 0; jj < 4; jj++) {
            int c = n0g + ng * 4 + jj;
            int h = c >> 5, d = c & 31;
            out[(((size_t)b * NH + h) * SQ + s) * DD + d] = acc[ii][jj];
        }
    }
}

// ---------------------------------------------------------------- k_rms
// in-place RMS over D=32 groups of (b,h,s)
__global__ __launch_bounds__(256) void k_rms(float* x, const float* w) {
    int g = blockIdx.x * 8 + (threadIdx.x >> 5);
    int d = threadIdx.x & 31;
    float* p = x + (size_t)g * DD + d;
    float v = *p;
    float s = v * v;
    for (int off = 16; off; off >>= 1) s += __shfl_xor(s, off, 32);
    float rs = rsqrtf(s * (1.0f / DD) + EPSV);
    *p = v * rs * w[d];
}

// ---------------------------------------------------------------- k_uv
// U[h] = sum_c lnw[c]*wz[c,h];  V[h] = sum_c lnb[c]*wz[c,h]  (48 floats)
__global__ __launch_bounds__(64) void k_uv(const float* wz, const float* lnw,
                                           const float* lnb, float* uv) {
    int t = threadIdx.x;
    if (t < 2 * NH) {
        int h = t % NH;
        const float* s = (t < NH) ? lnw : lnb;
        float a = 0.f;
        for (int c = 0; c < CZ; ++c) a += s[c] * wz[c * NH + h];
        uv[t] = a;
    }
}

// ---------------------------------------------------------------- k_zbias
// zbias[h,i,j] = bf16( rs*P[h] - mu*rs*U[h] + V[h] + maskbias )
#define ZROWS 64
#define ZSTRIDE 132
__global__ __launch_bounds__(256) void k_zbias(const float* z, const int* zmask,
                                               const float* wz, const float* lnw,
                                               const float* lnb, const float* uv,
                                               bf16* zbias) {
    __shared__ float zt[ZROWS * ZSTRIDE];   // 33792 B; reused for partials
    __shared__ bf16 ot[NH][ZROWS];          // 3 KiB output staging
    int t = threadIdx.x;
    size_t base = (size_t)blockIdx.x * ZROWS;
    const float4* src = (const float4*)(z + base * CZ);
    // ---- stage 64x128, coalesced float4, swizzled LDS placement
    #pragma unroll
    for (int it = 0; it < 8; it++) {
        int gi = t + it * 256;                 // float4 index in 32 KiB chunk
        int row = gi >> 5, c4 = gi & 31;
        int cs = (c4 * 4) ^ ((row >> 3) << 2); // channel-group swizzle
        *(float4*)&zt[row * ZSTRIDE + cs] = src[gi];
    }
    __syncthreads();
    int lane = t & 63;
    int qd = __builtin_amdgcn_readfirstlane(t >> 6);   // wave id = channel quarter
    int sw = (lane >> 3) << 2;
    float acc[NH];
    #pragma unroll
    for (int h = 0; h < NH; h++) acc[h] = 0.f;
    float s1 = 0.f, s2 = 0.f;
    #pragma unroll
    for (int i = 0; i < 8; i++) {
        int c0 = qd * 32 + i * 4;              // wave-uniform channel base
        float4 zv = *(const float4*)&zt[lane * ZSTRIDE + (c0 ^ sw)];
        float e[4] = {zv.x, zv.y, zv.z, zv.w};
        #pragma unroll
        for (int u = 0; u < 4; u++) {
            int c = c0 + u;                    // wave-uniform -> s_loads below
            float zval = e[u];
            s1 += zval;
            s2 = fmaf(zval, zval, s2);
            float tc = zval * lnw[c];
            #pragma unroll
            for (int h = 0; h < NH; h++)
                acc[h] = fmaf(tc, wz[c * NH + h], acc[h]);
        }
    }
    __syncthreads();   // all waves done reading zt -> safe to reuse as partials
    {
        float* pp = zt + qd * (ZROWS * 27) + lane * 27;
        pp[0] = s1; pp[1] = s2;
        #pragma unroll
        for (int h = 0; h < NH; h++) pp[2 + h] = acc[h];
    }
    __syncthreads();
    int r = lane;
    int hb = qd * 6;
    float fs1 = 0.f, fs2 = 0.f;
    float fa[6] = {};
    #pragma unroll
    for (int q = 0; q < 4; q++) {
        const float* p = zt + q * (ZROWS * 27) + r * 27;
        fs1 += p[0]; fs2 += p[1];
        #pragma unroll
        for (int j = 0; j < 6; j++) fa[j] += p[2 + hb + j];
    }
    float mu = fs1 * (1.0f / CZ);
    float var = fs2 * (1.0f / CZ) - mu * mu;
    float rs = rsqrtf(var + EPSV);
    float mb = (zmask[base + r] > 0) ? 0.0f : -1.0e9f;
    #pragma unroll
    for (int j = 0; j < 6; j++) {
        int h = hb + j;
        float val = rs * fa[j] - mu * rs * uv[h] + uv[NH + h] + mb;
        ot[h][r] = f2b(val);
    }
    __syncthreads();
    size_t SS = (size_t)SQ * SQ;
    if (t < 192) {
        int h = t >> 3, l8 = t & 7;
        uint4 val = *(const uint4*)&ot[h][l8 * 8];
        *(uint4*)&zbias[(size_t)h * SS + base + l8 * 8] = val;
    }
}

// ---------------------------------------------------------------- k_attn
// flash attention per (b,h, 64-row q tile), f16 MFMA (16x16x32, K = D = 32).
// 4 waves, wave w owns q-rows [w*16, w*16+16). Softmax state (m,l) replicated
// in registers across the 16 lanes sharing a row -> no LDS state, no extra
// barriers. A/B fragments use identical (group,elem)->k placement so the
// contraction is correct for any internal k-order (CDNA A/B maps symmetric).
// C/D mapping (HW-verified): col = lane&15, row = (lane>>4)*4 + reg.
#define PQK 40    // f16 pitch for Qs/Ks rows (80 B, 16B-aligned)
#define PPV 72    // f16 pitch for Ps/Vs rows (144 B, 16B-aligned)
__global__ __launch_bounds__(256) void k_attn(const float* q, const float* k,
                                              const float* v, const bf16* zbias,
                                              const float* beta, float* attn_out) {
    int qt = blockIdx.x;   // 0..15
    int bh = blockIdx.y;   // 0..47
    int b = bh / NH, h = bh % NH;
    __shared__ f16 Qs[64 * PQK];   // [i][d] scaled
    __shared__ f16 Ks[64 * PQK];   // [j][d]
    __shared__ f16 Vs[32 * PPV];   // [d][j]  (transposed)
    __shared__ f16 Ps[64 * PPV];   // [i][j]
    int t = threadIdx.x;
    int w = t >> 6, l = t & 63;
    int lg = l >> 4, ll = l & 15;
    const float scale = 0.17677669529663687f;   // 1/sqrt(32)
    size_t SS = (size_t)SQ * SQ;
    int srow = t >> 2, sc0 = (t & 3) * 8;       // staging map: 8 f32 per thread

    // ---- stage Q once (scaled)
    {
        const float* qb = q + ((size_t)bh * SQ + qt * 64) * DD;
        float4 a0 = *(const float4*)&qb[srow * DD + sc0];
        float4 a1 = *(const float4*)&qb[srow * DD + sc0 + 4];
        f16x8 hv;
        hv[0] = (f16)(a0.x * scale); hv[1] = (f16)(a0.y * scale);
        hv[2] = (f16)(a0.z * scale); hv[3] = (f16)(a0.w * scale);
        hv[4] = (f16)(a1.x * scale); hv[5] = (f16)(a1.y * scale);
        hv[6] = (f16)(a1.z * scale); hv[7] = (f16)(a1.w * scale);
        *(f16x8*)&Qs[srow * PQK + sc0] = hv;
    }
    f32x4 accO0 = {0.f, 0.f, 0.f, 0.f}, accO1 = {0.f, 0.f, 0.f, 0.f};
    float m_reg[4], l_reg[4];
    #pragma unroll
    for (int r = 0; r < 4; r++) { m_reg[r] = -3.0e38f; l_reg[r] = 0.f; }

    // prefetch K/V tile 0 into regs
    float4 kr0, kr1, vr0, vr1;
    {
        const float* kb = k + ((size_t)bh * SQ) * DD;
        const float* vb = v + ((size_t)bh * SQ) * DD;
        kr0 = *(const float4*)&kb[srow * DD + sc0];
        kr1 = *(const float4*)&kb[srow * DD + sc0 + 4];
        vr0 = *(const float4*)&vb[srow * DD + sc0];
        vr1 = *(const float4*)&vb[srow * DD + sc0 + 4];
    }
    __syncthreads();   // Qs visible
    // write K/V tile 0 to LDS
    {
        f16x8 hk;
        hk[0] = (f16)kr0.x; hk[1] = (f16)kr0.y; hk[2] = (f16)kr0.z; hk[3] = (f16)kr0.w;
        hk[4] = (f16)kr1.x; hk[5] = (f16)kr1.y; hk[6] = (f16)kr1.z; hk[7] = (f16)kr1.w;
        *(f16x8*)&Ks[srow * PQK + sc0] = hk;
        float vv[8] = {vr0.x, vr0.y, vr0.z, vr0.w, vr1.x, vr1.y, vr1.z, vr1.w};
        #pragma unroll
        for (int u = 0; u < 8; u++) Vs[(sc0 + u) * PPV + srow] = (f16)vv[u];
    }
    const unsigned short* zb = (const unsigned short*)(zbias + (size_t)h * SS);
    const float* bb = beta + (size_t)b * SS;
    int ibase = qt * 64 + w * 16 + lg * 4;

    for (int kt = 0; kt < 16; kt++) {
        __syncthreads();   // staged tile visible
        if (kt < 15) {     // prefetch next tile (global -> regs, hides latency)
            const float* kb = k + ((size_t)bh * SQ + (kt + 1) * 64) * DD;
            const float* vb = v + ((size_t)bh * SQ + (kt + 1) * 64) * DD;
            kr0 = *(const float4*)&kb[srow * DD + sc0];
            kr1 = *(const float4*)&kb[srow * DD + sc0 + 4];
            vr0 = *(const float4*)&vb[srow * DD + sc0];
            vr1 = *(const float4*)&vb[srow * DD + sc0 + 4];
        }
        // ---- C-init = bias (zbias bf16 + beta f32), C layout row=(lg*4+r) col=ll
        f32x4 acc[4];
        #pragma unroll
        for (int c = 0; c < 4; c++) {
            #pragma unroll
            for (int r = 0; r < 4; r++) {
                size_t off = (size_t)(ibase + r) * SQ + kt * 64 + c * 16 + ll;
                union { unsigned u; float f; } cv;
                cv.u = (unsigned)zb[off] << 16;
                acc[c][r] = cv.f + bb[off];
            }
        }
        // ---- QK^T: one MFMA per 16x16 tile (K = 32 in one shot)
        f16x8 aQ = *(const f16x8*)&Qs[(w * 16 + ll) * PQK + lg * 8];
        #pragma unroll
        for (int c = 0; c < 4; c++) {
            f16x8 bK = *(const f16x8*)&Ks[(c * 16 + ll) * PQK + lg * 8];
            acc[c] = __builtin_amdgcn_mfma_f32_16x16x32_f16(aQ, bK, acc[c], 0, 0, 0);
        }
        // ---- online softmax, state replicated across the 16 lanes of a row
        float al[4];
        #pragma unroll
        for (int r = 0; r < 4; r++) {
            float mx = fmaxf(fmaxf(acc[0][r], acc[1][r]), fmaxf(acc[2][r], acc[3][r]));
            #pragma unroll
            for (int off = 1; off < 16; off <<= 1) mx = fmaxf(mx, __shfl_xor(mx, off, 64));
            float mn = fmaxf(m_reg[r], mx);
            al[r] = __expf(m_reg[r] - mn);
            float ps = 0.f;
            #pragma unroll
            for (int c = 0; c < 4; c++) {
                float p = __expf(acc[c][r] - mn);
                acc[c][r] = p;
                ps += p;
            }
            #pragma unroll
            for (int off = 1; off < 16; off <<= 1) ps += __shfl_xor(ps, off, 64);
            m_reg[r] = mn;
            l_reg[r] = l_reg[r] * al[r] + ps;
        }
        // ---- P -> f16 LDS (wave-private rows)
        #pragma unroll
        for (int c = 0; c < 4; c++)
            #pragma unroll
            for (int r = 0; r < 4; r++)
                Ps[(w * 16 + lg * 4 + r) * PPV + c * 16 + ll] = (f16)acc[c][r];
        // rescale O
        #pragma unroll
        for (int r = 0; r < 4; r++) { accO0[r] *= al[r]; accO1[r] *= al[r]; }
        // wave-internal: ensure P writes landed before cross-lane P reads
        __asm__ volatile("s_waitcnt lgkmcnt(0)" ::: "memory");
        // ---- PV: [64 rows x 32 d] += P[64x64] @ V[64x32]
        #pragma unroll
        for (int jt = 0; jt < 2; jt++) {
            f16x8 aP = *(const f16x8*)&Ps[(w * 16 + ll) * PPV + jt * 32 + lg * 8];
            f16x8 bV0 = *(const f16x8*)&Vs[(ll) * PPV + jt * 32 + lg * 8];
            f16x8 bV1 = *(const f16x8*)&Vs[(16 + ll) * PPV + jt * 32 + lg * 8];
            accO0 = __builtin_amdgcn_mfma_f32_16x16x32_f16(aP, bV0, accO0, 0, 0, 0);
            accO1 = __builtin_amdgcn_mfma_f32_16x16x32_f16(aP, bV1, accO1, 0, 0, 0);
        }
        __syncthreads();   // all waves done reading Ks/Vs
        if (kt < 15) {     // write next tile regs -> LDS
            f16x8 hk;
            hk[0] = (f16)kr0.x; hk[1] = (f16)kr0.y; hk[2] = (f16)kr0.z; hk[3] = (f16)kr0.w;
            hk[4] = (f16)kr1.x; hk[5] = (f16)kr1.y; hk[6] = (f16)kr1.z; hk[7] = (f16)kr1.w;
            *(f16x8*)&Ks[srow * PQK + sc0] = hk;
            float vv[8] = {vr0.x, vr0.y, vr0.z, vr0.w, vr1.x, vr1.y, vr1.z, vr1.w};
            #pragma unroll
            for (int u = 0; u < 8; u++) Vs[(sc0 + u) * PPV + srow] = (f16)vv[u];
        }
    }
    // ---- epilogue: normalize + store (C layout -> coalesced 64B segments)
    #pragma unroll
    for (int r = 0; r < 4; r++) {
        float inv = 1.0f / l_reg[r];
        int row = qt * 64 + w * 16 + lg * 4 + r;
        float* op = attn_out + ((size_t)b * SQ + row) * CS + h * DD;
        op[ll] = accO0[r] * inv;
        op[16 + ll] = accO1[r] * inv;
    }
}

// ---------------------------------------------------------------- k_gemm_out
// out[r,c] = (A @ w_o + b_o[c]) * gate[b,c]   (fp32 out)
__global__ __launch_bounds__(256) void k_gemm_out(const float* A, const float* W,
                                                  const float* b_o, const float* emb,
                                                  float* out) {
    __shared__ float As[16][68];
    __shared__ float Bs[16][68];
    int t = threadIdx.x;
    int m0g = blockIdx.x * 64;
    int n0g = blockIdx.y * 64;
    int mg = t >> 4, ng = t & 15;
    float acc[4][4] = {};
    for (int k0 = 0; k0 < CS; k0 += 16) {
        {
            int kk = t & 15, mm = t >> 4;
            #pragma unroll
            for (int r = 0; r < 4; r++)
                As[kk][mm + r * 16] = A[(size_t)(m0g + mm + r * 16) * CS + k0 + kk];
            int nn = (t & 15) * 4, kb = t >> 4;
            float4 w4 = *(const float4*)&W[(size_t)(k0 + kb) * CS + n0g + nn];
            *(float4*)&Bs[kb][nn] = w4;
        }
        __syncthreads();
        #pragma unroll
        for (int kk = 0; kk < 16; kk++) {
            float4 a4 = *(const float4*)&As[kk][mg * 4];
            float4 b4 = *(const float4*)&Bs[kk][ng * 4];
            float a[4] = {a4.x, a4.y, a4.z, a4.w};
            float bv[4] = {b4.x, b4.y, b4.z, b4.w};
            #pragma unroll
            for (int ii = 0; ii < 4; ii++)
                #pragma unroll
                for (int jj = 0; jj < 4; jj++)
                    acc[ii][jj] += a[ii] * bv[jj];
        }
        __syncthreads();
    }
    #pragma unroll
    for (int ii = 0; ii < 4; ii++) {
        int r = m0g + mg * 4 + ii;
        int b = r >> 10;
        int c0 = n0g + ng * 4;
        const float* gt = emb + (size_t)b * 3 * CS + 2 * CS;
        float4 o4;
        o4.x = (acc[ii][0] + b_o[c0 + 0]) * gt[c0 + 0];
        o4.y = (acc[ii][1] + b_o[c0 + 1]) * gt[c0 + 1];
        o4.z = (acc[ii][2] + b_o[c0 + 2]) * gt[c0 + 2];
        o4.w = (acc[ii][3] + b_o[c0 + 3]) * gt[c0 + 3];
        *(float4*)&out[(size_t)r * CS + c0] = o4;
    }
}

// ---------------------------------------------------------------- launch
extern "C" void kernel_launch(void* const* d_in, const int* in_sizes, int n_in,
                              void* d_out, int out_size, void* d_ws, size_t ws_size,
                              hipStream_t stream) {
    const float* bs      = (const float*)d_in[0];
    const float* z       = (const float*)d_in[1];
    const float* t       = (const float*)d_in[2];
    const float* beta    = (const float*)d_in[3];
    const int*   z_mask  = (const int*)d_in[4];
    const float* w_adaln = (const float*)d_in[5];
    const float* b_adaln = (const float*)d_in[6];
    const float* ln_z_w  = (const float*)d_in[7];
    const float* ln_z_b  = (const float*)d_in[8];
    const float* w_q     = (const float*)d_in[9];
    const float* w_k     = (const float*)d_in[10];
    const float* w_v     = (const float*)d_in[11];
    const float* w_z     = (const float*)d_in[12];
    const float* rms_q_w = (const float*)d_in[13];
    const float* rms_k_w = (const float*)d_in[14];
    const float* w_o     = (const float*)d_in[15];
    const float* b_o     = (const float*)d_in[16];
    float* out = (float*)d_out;

    char* ws = (char*)d_ws;
    const size_t SZ_QKV = (size_t)2 * SQ * CS * 4;   // 6291456
    float* emb   = (float*)(ws);                      // 2*2304*4 = 18432
    float* bsn   = (float*)(ws + 32768);
    float* qbuf  = (float*)(ws + 32768 + SZ_QKV);
    float* kbuf  = (float*)(ws + 32768 + 2 * SZ_QKV);
    float* vbuf  = (float*)(ws + 32768 + 3 * SZ_QKV);
    float* attn  = (float*)(ws + 32768 + 4 * SZ_QKV);
    bf16*  zbias = (bf16*)(ws + 32768 + 5 * SZ_QKV);  // 24*1024*1024*2 = 50331648
    float* uv    = (float*)(ws + 32768 + 5 * SZ_QKV + 50331648);  // 48 floats

    k_adaln<<<dim3(9, 2), 256, 0, stream>>>(t, w_adaln, b_adaln, emb);
    k_uv<<<1, 64, 0, stream>>>(w_z, ln_z_w, ln_z_b, uv);
    k_bsnorm<<<2048, 256, 0, stream>>>(bs, emb, bsn);
    k_gemm_qkv<<<dim3(32, 12), 256, 0, stream>>>(bsn, w_q, qbuf);
    k_gemm_qkv<<<dim3(32, 12), 256, 0, stream>>>(bsn, w_k, kbuf);
    k_gemm_qkv<<<dim3(32, 12), 256, 0, stream>>>(bsn, w_v, vbuf);
    k_rms<<<6144, 256, 0, stream>>>(qbuf, rms_q_w);
    k_rms<<<6144, 256, 0, stream>>>(kbuf, rms_k_w);
    k_zbias<<<16384, 256, 0, stream>>>(z, z_mask, w_z, ln_z_w, ln_z_b, uv, zbias);
    k_attn<<<dim3(16, 48), 256, 0, stream>>>(qbuf, kbuf, vbuf, zbias, beta, attn);
    k_gemm_out<<<dim3(32, 12), 256, 0, stream>>>(attn, w_o, b_o, emb, out);
}

// Round 4
// 920.590 us; speedup vs baseline: 2.9060x; 1.2036x over previous
//
#include <hip/hip_runtime.h>
#include <hip/hip_bf16.h>
#include <math.h>

#define SQ 1024       // sequence length
#define CS 768        // channels
#define CZ 128        // z channels
#define DD 32         // head dim
#define NH 24         // heads
#define EPSV 1e-5f

typedef __hip_bfloat16 bf16;
typedef _Float16 f16;
typedef _Float16 f16x8 __attribute__((ext_vector_type(8)));
typedef _Float16 f16x4 __attribute__((ext_vector_type(4)));
typedef float f32x4 __attribute__((ext_vector_type(4)));

__device__ __forceinline__ float b2f(bf16 x) { return __bfloat162float(x); }
__device__ __forceinline__ bf16 f2b(float x) { return __float2bfloat16(x); }

// ---------------------------------------------------------------- k_adaln
// emb[b][o] = silu(t[b]) @ w_adaln[:,o] + b_adaln[o]   (o < 2304)
__global__ __launch_bounds__(256) void k_adaln(const float* t, const float* w,
                                               const float* bias, float* emb) {
    __shared__ float st[CS];
    int b = blockIdx.y;
    int o = blockIdx.x * 256 + threadIdx.x;
    for (int c = threadIdx.x; c < CS; c += 256) {
        float x = t[b * CS + c];
        st[c] = x / (1.0f + __expf(-x));
    }
    __syncthreads();
    float acc = bias[o];
    for (int c = 0; c < CS; ++c)
        acc += st[c] * w[(size_t)c * (3 * CS) + o];
    emb[(size_t)b * 3 * CS + o] = acc;
}

// ---------------------------------------------------------------- k_bsnorm
// bsn[b,s,c] = f16( LN(bs[b,s,:])[c] * (1+scale[b,c]) + shift[b,c] )
__global__ __launch_bounds__(256) void k_bsnorm(const float* bs, const float* emb,
                                                f16* bsn) {
    int row = blockIdx.x;              // b*SQ + s
    int b = row >> 10;
    const float* x = bs + (size_t)row * CS;
    float v[3], s1 = 0.f, s2 = 0.f;
    #pragma unroll
    for (int i = 0; i < 3; i++) {
        float f = x[threadIdx.x + i * 256];
        v[i] = f; s1 += f; s2 += f * f;
    }
    __shared__ float red[8];
    for (int off = 32; off; off >>= 1) { s1 += __shfl_down(s1, off); s2 += __shfl_down(s2, off); }
    int wid = threadIdx.x >> 6;
    if ((threadIdx.x & 63) == 0) { red[wid] = s1; red[wid + 4] = s2; }
    __syncthreads();
    s1 = red[0] + red[1] + red[2] + red[3];
    s2 = red[4] + red[5] + red[6] + red[7];
    float mu = s1 * (1.0f / CS);
    float var = s2 * (1.0f / CS) - mu * mu;
    float rs = rsqrtf(var + EPSV);
    const float* sh = emb + (size_t)b * 3 * CS;
    f16* o = bsn + (size_t)row * CS;
    #pragma unroll
    for (int i = 0; i < 3; i++) {
        int c = threadIdx.x + i * 256;
        o[c] = (f16)((v[i] - mu) * rs * (1.0f + sh[CS + c]) + sh[c]);
    }
}

// ---------------------------------------------------------------- k_wt
// transpose+convert one 64x64 tile of W[k][n] f32 -> WT[n][k] f16 (4 matrices)
__global__ __launch_bounds__(256) void k_wt(const float* wq, const float* wk,
                                            const float* wv, const float* wo,
                                            f16* wt) {
    int z = blockIdx.z;
    const float* W = (z == 0) ? wq : (z == 1) ? wk : (z == 2) ? wv : wo;
    f16* WT = wt + (size_t)z * CS * CS;
    __shared__ float ts[64][68];
    int t = threadIdx.x;
    int k0 = blockIdx.x * 64, n0 = blockIdx.y * 64;
    #pragma unroll
    for (int i = 0; i < 4; i++) {
        int kr = (t >> 4) + i * 16, nc = (t & 15) * 4;
        float4 v4 = *(const float4*)&W[(size_t)(k0 + kr) * CS + n0 + nc];
        ts[kr][nc] = v4.x; ts[kr][nc + 1] = v4.y;
        ts[kr][nc + 2] = v4.z; ts[kr][nc + 3] = v4.w;
    }
    __syncthreads();
    #pragma unroll
    for (int i = 0; i < 4; i++) {
        int nr = (t >> 4) + i * 16, kc = (t & 15) * 4;
        f16x4 h4;
        h4[0] = (f16)ts[kc][nr]; h4[1] = (f16)ts[kc + 1][nr];
        h4[2] = (f16)ts[kc + 2][nr]; h4[3] = (f16)ts[kc + 3][nr];
        *(f16x4*)&WT[(size_t)(n0 + nr) * CS + k0 + kc] = h4;
    }
}

// ---------------------------------------------------------------- k_gemm16
// C[2048 x 768] = A(f16 [m][k]) @ WT(f16 [n][k])^T, fp32 MFMA accumulate.
// BM=128 BN=64 BK=32; 4 waves: wave w owns rows (w>>1)*64, cols (w&1)*32.
// Fragment discipline identical to (HW-verified) k_attn: A/B frag row via
// lane&15, k via (lane>>4)*8; C/D row=(lane>>4)*4+reg, col=lane&15.
// MODE 0: out = qkv buffer (b,h,s,d) fp32, z = blockIdx.z in {q,k,v}, with
//         fused RMS over d (z<2): a wave's 32-col slice is exactly one head.
// MODE 1: out[r*CS+c] = (acc + b_o[c]) * gate[b,c]  (fp32 d_out)
#define GP 40   // f16 LDS row pitch (80 B: 16B-aligned, 2-way banks = free)
template<int MODE>
__global__ __launch_bounds__(256) void k_gemm16(const f16* A, const f16* WT,
                                                float* out, const float* rwq,
                                                const float* rwk, const float* b_o,
                                                const float* emb) {
    __shared__ f16 As[128 * GP];
    __shared__ f16 Ws[64 * GP];
    int t = threadIdx.x;
    int m0 = blockIdx.x * 128, n0 = blockIdx.y * 64;
    int z = blockIdx.z;
    const f16* Ab = A + (size_t)m0 * CS;
    const f16* Wb = WT + (size_t)z * CS * CS + (size_t)n0 * CS;
    if (MODE == 0) out += (size_t)z * ((size_t)2 * SQ * CS);
    int w = t >> 6, l = t & 63;
    int lg = l >> 4, ll = l & 15;
    int wr = w >> 1, wc = w & 1;
    int sr = t >> 2, sk = (t & 3) * 8;
    f32x4 acc[4][2] = {};
    for (int k0 = 0; k0 < CS; k0 += 32) {
        #pragma unroll
        for (int it = 0; it < 2; it++) {
            int r = sr + it * 64;
            *(f16x8*)&As[r * GP + sk] = *(const f16x8*)&Ab[(size_t)r * CS + k0 + sk];
        }
        *(f16x8*)&Ws[sr * GP + sk] = *(const f16x8*)&Wb[(size_t)sr * CS + k0 + sk];
        __syncthreads();
        f16x8 af[4], bf[2];
        #pragma unroll
        for (int mi = 0; mi < 4; mi++)
            af[mi] = *(const f16x8*)&As[(wr * 64 + mi * 16 + ll) * GP + lg * 8];
        #pragma unroll
        for (int ni = 0; ni < 2; ni++)
            bf[ni] = *(const f16x8*)&Ws[(wc * 32 + ni * 16 + ll) * GP + lg * 8];
        #pragma unroll
        for (int mi = 0; mi < 4; mi++)
            #pragma unroll
            for (int ni = 0; ni < 2; ni++)
                acc[mi][ni] = __builtin_amdgcn_mfma_f32_16x16x32_f16(
                    af[mi], bf[ni], acc[mi][ni], 0, 0, 0);
        __syncthreads();
    }
    int c0 = n0 + wc * 32;
    const float* rw = (z == 0) ? rwq : rwk;
    #pragma unroll
    for (int mi = 0; mi < 4; mi++) {
        #pragma unroll
        for (int rg = 0; rg < 4; rg++) {
            int r = m0 + wr * 64 + mi * 16 + lg * 4 + rg;
            int bb = r >> 10, s = r & 1023;
            float v0 = acc[mi][0][rg], v1 = acc[mi][1][rg];
            if (MODE == 0) {
                if (z < 2) {   // fused RMS over the head's 32 d-values
                    float sq = v0 * v0 + v1 * v1;
                    sq += __shfl_xor(sq, 1); sq += __shfl_xor(sq, 2);
                    sq += __shfl_xor(sq, 4); sq += __shfl_xor(sq, 8);
                    float rs = rsqrtf(sq * (1.0f / DD) + EPSV);
                    v0 *= rs * rw[ll];
                    v1 *= rs * rw[16 + ll];
                }
                int h = c0 >> 5;
                float* op = out + (((size_t)bb * NH + h) * SQ + s) * DD;
                op[ll] = v0;
                op[16 + ll] = v1;
            } else {
                const float* gt = emb + (size_t)bb * 3 * CS + 2 * CS;
                out[(size_t)r * CS + c0 + ll] = (v0 + b_o[c0 + ll]) * gt[c0 + ll];
                out[(size_t)r * CS + c0 + 16 + ll] =
                    (v1 + b_o[c0 + 16 + ll]) * gt[c0 + 16 + ll];
            }
        }
    }
}

// ---------------------------------------------------------------- k_uv
// U[h] = sum_c lnw[c]*wz[c,h];  V[h] = sum_c lnb[c]*wz[c,h]  (48 floats)
__global__ __launch_bounds__(64) void k_uv(const float* wz, const float* lnw,
                                           const float* lnb, float* uv) {
    int t = threadIdx.x;
    if (t < 2 * NH) {
        int h = t % NH;
        const float* s = (t < NH) ? lnw : lnb;
        float a = 0.f;
        for (int c = 0; c < CZ; ++c) a += s[c] * wz[c * NH + h];
        uv[t] = a;
    }
}

// ---------------------------------------------------------------- k_zbias
// zbias[h,i,j] = bf16( rs*P[h] - mu*rs*U[h] + V[h] + maskbias )
#define ZROWS 64
#define ZSTRIDE 132
__global__ __launch_bounds__(256) void k_zbias(const float* z, const int* zmask,
                                               const float* wz, const float* lnw,
                                               const float* lnb, const float* uv,
                                               bf16* zbias) {
    __shared__ float zt[ZROWS * ZSTRIDE];   // 33792 B; reused for partials
    __shared__ bf16 ot[NH][ZROWS];          // 3 KiB output staging
    int t = threadIdx.x;
    size_t base = (size_t)blockIdx.x * ZROWS;
    const float4* src = (const float4*)(z + base * CZ);
    // ---- stage 64x128, coalesced float4, swizzled LDS placement
    #pragma unroll
    for (int it = 0; it < 8; it++) {
        int gi = t + it * 256;                 // float4 index in 32 KiB chunk
        int row = gi >> 5, c4 = gi & 31;
        int cs = (c4 * 4) ^ ((row >> 3) << 2); // channel-group swizzle
        *(float4*)&zt[row * ZSTRIDE + cs] = src[gi];
    }
    __syncthreads();
    int lane = t & 63;
    int qd = __builtin_amdgcn_readfirstlane(t >> 6);   // wave id = channel quarter
    int sw = (lane >> 3) << 2;
    float acc[NH];
    #pragma unroll
    for (int h = 0; h < NH; h++) acc[h] = 0.f;
    float s1 = 0.f, s2 = 0.f;
    #pragma unroll
    for (int i = 0; i < 8; i++) {
        int c0 = qd * 32 + i * 4;              // wave-uniform channel base
        float4 zv = *(const float4*)&zt[lane * ZSTRIDE + (c0 ^ sw)];
        float e[4] = {zv.x, zv.y, zv.z, zv.w};
        #pragma unroll
        for (int u = 0; u < 4; u++) {
            int c = c0 + u;                    // wave-uniform -> s_loads below
            float zval = e[u];
            s1 += zval;
            s2 = fmaf(zval, zval, s2);
            float tc = zval * lnw[c];
            #pragma unroll
            for (int h = 0; h < NH; h++)
                acc[h] = fmaf(tc, wz[c * NH + h], acc[h]);
        }
    }
    __syncthreads();   // all waves done reading zt -> safe to reuse as partials
    {
        float* pp = zt + qd * (ZROWS * 27) + lane * 27;
        pp[0] = s1; pp[1] = s2;
        #pragma unroll
        for (int h = 0; h < NH; h++) pp[2 + h] = acc[h];
    }
    __syncthreads();
    int r = lane;
    int hb = qd * 6;
    float fs1 = 0.f, fs2 = 0.f;
    float fa[6] = {};
    #pragma unroll
    for (int q = 0; q < 4; q++) {
        const float* p = zt + q * (ZROWS * 27) + r * 27;
        fs1 += p[0]; fs2 += p[1];
        #pragma unroll
        for (int j = 0; j < 6; j++) fa[j] += p[2 + hb + j];
    }
    float mu = fs1 * (1.0f / CZ);
    float var = fs2 * (1.0f / CZ) - mu * mu;
    float rs = rsqrtf(var + EPSV);
    float mb = (zmask[base + r] > 0) ? 0.0f : -1.0e9f;
    #pragma unroll
    for (int j = 0; j < 6; j++) {
        int h = hb + j;
        float val = rs * fa[j] - mu * rs * uv[h] + uv[NH + h] + mb;
        ot[h][r] = f2b(val);
    }
    __syncthreads();
    size_t SS = (size_t)SQ * SQ;
    if (t < 192) {
        int h = t >> 3, l8 = t & 7;
        uint4 val = *(const uint4*)&ot[h][l8 * 8];
        *(uint4*)&zbias[(size_t)h * SS + base + l8 * 8] = val;
    }
}

// ---------------------------------------------------------------- k_attn
// flash attention per (b,h, 64-row q tile), f16 MFMA (16x16x32, K = D = 32).
#define PQK 40    // f16 pitch for Qs/Ks rows (80 B, 16B-aligned)
#define PPV 72    // f16 pitch for Ps/Vs rows (144 B, 16B-aligned)
__global__ __launch_bounds__(256) void k_attn(const float* q, const float* k,
                                              const float* v, const bf16* zbias,
                                              const float* beta, f16* attn_out) {
    int qt = blockIdx.x;   // 0..15
    int bh = blockIdx.y;   // 0..47
    int b = bh / NH, h = bh % NH;
    __shared__ f16 Qs[64 * PQK];   // [i][d] scaled
    __shared__ f16 Ks[64 * PQK];   // [j][d]
    __shared__ f16 Vs[32 * PPV];   // [d][j]  (transposed)
    __shared__ f16 Ps[64 * PPV];   // [i][j]
    int t = threadIdx.x;
    int w = t >> 6, l = t & 63;
    int lg = l >> 4, ll = l & 15;
    const float scale = 0.17677669529663687f;   // 1/sqrt(32)
    size_t SS = (size_t)SQ * SQ;
    int srow = t >> 2, sc0 = (t & 3) * 8;       // staging map: 8 f32 per thread

    // ---- stage Q once (scaled)
    {
        const float* qb = q + ((size_t)bh * SQ + qt * 64) * DD;
        float4 a0 = *(const float4*)&qb[srow * DD + sc0];
        float4 a1 = *(const float4*)&qb[srow * DD + sc0 + 4];
        f16x8 hv;
        hv[0] = (f16)(a0.x * scale); hv[1] = (f16)(a0.y * scale);
        hv[2] = (f16)(a0.z * scale); hv[3] = (f16)(a0.w * scale);
        hv[4] = (f16)(a1.x * scale); hv[5] = (f16)(a1.y * scale);
        hv[6] = (f16)(a1.z * scale); hv[7] = (f16)(a1.w * scale);
        *(f16x8*)&Qs[srow * PQK + sc0] = hv;
    }
    f32x4 accO0 = {0.f, 0.f, 0.f, 0.f}, accO1 = {0.f, 0.f, 0.f, 0.f};
    float m_reg[4], l_reg[4];
    #pragma unroll
    for (int r = 0; r < 4; r++) { m_reg[r] = -3.0e38f; l_reg[r] = 0.f; }

    // prefetch K/V tile 0 into regs
    float4 kr0, kr1, vr0, vr1;
    {
        const float* kb = k + ((size_t)bh * SQ) * DD;
        const float* vb = v + ((size_t)bh * SQ) * DD;
        kr0 = *(const float4*)&kb[srow * DD + sc0];
        kr1 = *(const float4*)&kb[srow * DD + sc0 + 4];
        vr0 = *(const float4*)&vb[srow * DD + sc0];
        vr1 = *(const float4*)&vb[srow * DD + sc0 + 4];
    }
    __syncthreads();   // Qs visible
    // write K/V tile 0 to LDS
    {
        f16x8 hk;
        hk[0] = (f16)kr0.x; hk[1] = (f16)kr0.y; hk[2] = (f16)kr0.z; hk[3] = (f16)kr0.w;
        hk[4] = (f16)kr1.x; hk[5] = (f16)kr1.y; hk[6] = (f16)kr1.z; hk[7] = (f16)kr1.w;
        *(f16x8*)&Ks[srow * PQK + sc0] = hk;
        float vv[8] = {vr0.x, vr0.y, vr0.z, vr0.w, vr1.x, vr1.y, vr1.z, vr1.w};
        #pragma unroll
        for (int u = 0; u < 8; u++) Vs[(sc0 + u) * PPV + srow] = (f16)vv[u];
    }
    const unsigned short* zb = (const unsigned short*)(zbias + (size_t)h * SS);
    const float* bb = beta + (size_t)b * SS;
    int ibase = qt * 64 + w * 16 + lg * 4;

    for (int kt = 0; kt < 16; kt++) {
        __syncthreads();   // staged tile visible
        if (kt < 15) {     // prefetch next tile (global -> regs, hides latency)
            const float* kb = k + ((size_t)bh * SQ + (kt + 1) * 64) * DD;
            const float* vb = v + ((size_t)bh * SQ + (kt + 1) * 64) * DD;
            kr0 = *(const float4*)&kb[srow * DD + sc0];
            kr1 = *(const float4*)&kb[srow * DD + sc0 + 4];
            vr0 = *(const float4*)&vb[srow * DD + sc0];
            vr1 = *(const float4*)&vb[srow * DD + sc0 + 4];
        }
        // ---- C-init = bias (zbias bf16 + beta f32), C layout row=(lg*4+r) col=ll
        f32x4 acc[4];
        #pragma unroll
        for (int c = 0; c < 4; c++) {
            #pragma unroll
            for (int r = 0; r < 4; r++) {
                size_t off = (size_t)(ibase + r) * SQ + kt * 64 + c * 16 + ll;
                union { unsigned u; float f; } cv;
                cv.u = (unsigned)zb[off] << 16;
                acc[c][r] = cv.f + bb[off];
            }
        }
        // ---- QK^T: one MFMA per 16x16 tile (K = 32 in one shot)
        f16x8 aQ = *(const f16x8*)&Qs[(w * 16 + ll) * PQK + lg * 8];
        #pragma unroll
        for (int c = 0; c < 4; c++) {
            f16x8 bK = *(const f16x8*)&Ks[(c * 16 + ll) * PQK + lg * 8];
            acc[c] = __builtin_amdgcn_mfma_f32_16x16x32_f16(aQ, bK, acc[c], 0, 0, 0);
        }
        // ---- online softmax, state replicated across the 16 lanes of a row
        float al[4];
        #pragma unroll
        for (int r = 0; r < 4; r++) {
            float mx = fmaxf(fmaxf(acc[0][r], acc[1][r]), fmaxf(acc[2][r], acc[3][r]));
            #pragma unroll
            for (int off = 1; off < 16; off <<= 1) mx = fmaxf(mx, __shfl_xor(mx, off, 64));
            float mn = fmaxf(m_reg[r], mx);
            al[r] = __expf(m_reg[r] - mn);
            float ps = 0.f;
            #pragma unroll
            for (int c = 0; c < 4; c++) {
                float p = __expf(acc[c][r] - mn);
                acc[c][r] = p;
                ps += p;
            }
            #pragma unroll
            for (int off = 1; off < 16; off <<= 1) ps += __shfl_xor(ps, off, 64);
            m_reg[r] = mn;
            l_reg[r] = l_reg[r] * al[r] + ps;
        }
        // ---- P -> f16 LDS (wave-private rows)
        #pragma unroll
        for (int c = 0; c < 4; c++)
            #pragma unroll
            for (int r = 0; r < 4; r++)
                Ps[(w * 16 + lg * 4 + r) * PPV + c * 16 + ll] = (f16)acc[c][r];
        // rescale O
        #pragma unroll
        for (int r = 0; r < 4; r++) { accO0[r] *= al[r]; accO1[r] *= al[r]; }
        // wave-internal: ensure P writes landed before cross-lane P reads
        __asm__ volatile("s_waitcnt lgkmcnt(0)" ::: "memory");
        // ---- PV: [64 rows x 32 d] += P[64x64] @ V[64x32]
        #pragma unroll
        for (int jt = 0; jt < 2; jt++) {
            f16x8 aP = *(const f16x8*)&Ps[(w * 16 + ll) * PPV + jt * 32 + lg * 8];
            f16x8 bV0 = *(const f16x8*)&Vs[(ll) * PPV + jt * 32 + lg * 8];
            f16x8 bV1 = *(const f16x8*)&Vs[(16 + ll) * PPV + jt * 32 + lg * 8];
            accO0 = __builtin_amdgcn_mfma_f32_16x16x32_f16(aP, bV0, accO0, 0, 0, 0);
            accO1 = __builtin_amdgcn_mfma_f32_16x16x32_f16(aP, bV1, accO1, 0, 0, 0);
        }
        __syncthreads();   // all waves done reading Ks/Vs
        if (kt < 15) {     // write next tile regs -> LDS
            f16x8 hk;
            hk[0] = (f16)kr0.x; hk[1] = (f16)kr0.y; hk[2] = (f16)kr0.z; hk[3] = (f16)kr0.w;
            hk[4] = (f16)kr1.x; hk[5] = (f16)kr1.y; hk[6] = (f16)kr1.z; hk[7] = (f16)kr1.w;
            *(f16x8*)&Ks[srow * PQK + sc0] = hk;
            float vv[8] = {vr0.x, vr0.y, vr0.z, vr0.w, vr1.x, vr1.y, vr1.z, vr1.w};
            #pragma unroll
            for (int u = 0; u < 8; u++) Vs[(sc0 + u) * PPV + srow] = (f16)vv[u];
        }
    }
    // ---- epilogue: normalize + store f16 (feeds k_gemm16<1> directly)
    #pragma unroll
    for (int r = 0; r < 4; r++) {
        float inv = 1.0f / l_reg[r];
        int row = qt * 64 + w * 16 + lg * 4 + r;
        f16* op = attn_out + ((size_t)b * SQ + row) * CS + h * DD;
        op[ll] = (f16)(accO0[r] * inv);
        op[16 + ll] = (f16)(accO1[r] * inv);
    }
}

// ---------------------------------------------------------------- launch
extern "C" void kernel_launch(void* const* d_in, const int* in_sizes, int n_in,
                              void* d_out, int out_size, void* d_ws, size_t ws_size,
                              hipStream_t stream) {
    const float* bs      = (const float*)d_in[0];
    const float* z       = (const float*)d_in[1];
    const float* t       = (const float*)d_in[2];
    const float* beta    = (const float*)d_in[3];
    const int*   z_mask  = (const int*)d_in[4];
    const float* w_adaln = (const float*)d_in[5];
    const float* b_adaln = (const float*)d_in[6];
    const float* ln_z_w  = (const float*)d_in[7];
    const float* ln_z_b  = (const float*)d_in[8];
    const float* w_q     = (const float*)d_in[9];
    const float* w_k     = (const float*)d_in[10];
    const float* w_v     = (const float*)d_in[11];
    const float* w_z     = (const float*)d_in[12];
    const float* rms_q_w = (const float*)d_in[13];
    const float* rms_k_w = (const float*)d_in[14];
    const float* w_o     = (const float*)d_in[15];
    const float* b_o     = (const float*)d_in[16];
    float* out = (float*)d_out;

    char* ws = (char*)d_ws;
    const size_t SZ_QKV = (size_t)2 * SQ * CS * 4;   // 6291456 (fp32 qkv slot)
    float* emb   = (float*)(ws);                      // 2*2304*4 = 18432
    f16*   bsn   = (f16*)(ws + 32768);                // f16 2048x768 (slot reused)
    float* qbuf  = (float*)(ws + 32768 + SZ_QKV);     // q,k,v contiguous fp32
    float* kbuf  = (float*)(ws + 32768 + 2 * SZ_QKV);
    float* vbuf  = (float*)(ws + 32768 + 3 * SZ_QKV);
    f16*   attn  = (f16*)(ws + 32768 + 4 * SZ_QKV);   // f16 2048x768
    bf16*  zbias = (bf16*)(ws + 32768 + 5 * SZ_QKV);  // 24*1024*1024*2 = 50331648
    float* uv    = (float*)(ws + 32768 + 5 * SZ_QKV + 50331648);  // 48 floats
    f16*   wt    = (f16*)(ws + 32768 + 5 * SZ_QKV + 50331648 + 4096); // 4x768x768 f16

    k_adaln<<<dim3(9, 2), 256, 0, stream>>>(t, w_adaln, b_adaln, emb);
    k_uv<<<1, 64, 0, stream>>>(w_z, ln_z_w, ln_z_b, uv);
    k_wt<<<dim3(12, 12, 4), 256, 0, stream>>>(w_q, w_k, w_v, w_o, wt);
    k_bsnorm<<<2048, 256, 0, stream>>>(bs, emb, bsn);
    k_gemm16<0><<<dim3(16, 12, 3), 256, 0, stream>>>(bsn, wt, qbuf, rms_q_w,
                                                     rms_k_w, nullptr, nullptr);
    k_zbias<<<16384, 256, 0, stream>>>(z, z_mask, w_z, ln_z_w, ln_z_b, uv, zbias);
    k_attn<<<dim3(16, 48), 256, 0, stream>>>(qbuf, kbuf, vbuf, zbias, beta, attn);
    k_gemm16<1><<<dim3(16, 12, 1), 256, 0, stream>>>(attn, wt + (size_t)3 * CS * CS,
                                                     out, nullptr, nullptr, b_o, emb);
}

// Round 5
// 915.422 us; speedup vs baseline: 2.9224x; 1.0056x over previous
//
#include <hip/hip_runtime.h>
#include <hip/hip_bf16.h>
#include <math.h>

#define SQ 1024       // sequence length
#define CS 768        // channels
#define CZ 128        // z channels
#define DD 32         // head dim
#define NH 24         // heads
#define EPSV 1e-5f

typedef __hip_bfloat16 bf16;
typedef _Float16 f16;
typedef _Float16 f16x8 __attribute__((ext_vector_type(8)));
typedef _Float16 f16x4 __attribute__((ext_vector_type(4)));
typedef float f32x4 __attribute__((ext_vector_type(4)));

__device__ __forceinline__ float b2f(bf16 x) { return __bfloat162float(x); }
__device__ __forceinline__ bf16 f2b(float x) { return __float2bfloat16(x); }

// ---------------------------------------------------------------- k_adaln
// emb[b][o] = silu(t[b]) @ w_adaln[:,o] + b_adaln[o]   (o < 2304)
__global__ __launch_bounds__(256) void k_adaln(const float* t, const float* w,
                                               const float* bias, float* emb) {
    __shared__ float st[CS];
    int b = blockIdx.y;
    int o = blockIdx.x * 256 + threadIdx.x;
    for (int c = threadIdx.x; c < CS; c += 256) {
        float x = t[b * CS + c];
        st[c] = x / (1.0f + __expf(-x));
    }
    __syncthreads();
    float acc = bias[o];
    for (int c = 0; c < CS; ++c)
        acc += st[c] * w[(size_t)c * (3 * CS) + o];
    emb[(size_t)b * 3 * CS + o] = acc;
}

// ---------------------------------------------------------------- k_bsnorm
// bsn[b,s,c] = f16( LN(bs[b,s,:])[c] * (1+scale[b,c]) + shift[b,c] )
__global__ __launch_bounds__(256) void k_bsnorm(const float* bs, const float* emb,
                                                f16* bsn) {
    int row = blockIdx.x;              // b*SQ + s
    int b = row >> 10;
    const float* x = bs + (size_t)row * CS;
    float v[3], s1 = 0.f, s2 = 0.f;
    #pragma unroll
    for (int i = 0; i < 3; i++) {
        float f = x[threadIdx.x + i * 256];
        v[i] = f; s1 += f; s2 += f * f;
    }
    __shared__ float red[8];
    for (int off = 32; off; off >>= 1) { s1 += __shfl_down(s1, off); s2 += __shfl_down(s2, off); }
    int wid = threadIdx.x >> 6;
    if ((threadIdx.x & 63) == 0) { red[wid] = s1; red[wid + 4] = s2; }
    __syncthreads();
    s1 = red[0] + red[1] + red[2] + red[3];
    s2 = red[4] + red[5] + red[6] + red[7];
    float mu = s1 * (1.0f / CS);
    float var = s2 * (1.0f / CS) - mu * mu;
    float rs = rsqrtf(var + EPSV);
    const float* sh = emb + (size_t)b * 3 * CS;
    f16* o = bsn + (size_t)row * CS;
    #pragma unroll
    for (int i = 0; i < 3; i++) {
        int c = threadIdx.x + i * 256;
        o[c] = (f16)((v[i] - mu) * rs * (1.0f + sh[CS + c]) + sh[c]);
    }
}

// ---------------------------------------------------------------- k_wt
// transpose+convert one 64x64 tile of W[k][n] f32 -> WT[n][k] f16 (4 matrices)
__global__ __launch_bounds__(256) void k_wt(const float* wq, const float* wk,
                                            const float* wv, const float* wo,
                                            f16* wt) {
    int z = blockIdx.z;
    const float* W = (z == 0) ? wq : (z == 1) ? wk : (z == 2) ? wv : wo;
    f16* WT = wt + (size_t)z * CS * CS;
    __shared__ float ts[64][68];
    int t = threadIdx.x;
    int k0 = blockIdx.x * 64, n0 = blockIdx.y * 64;
    #pragma unroll
    for (int i = 0; i < 4; i++) {
        int kr = (t >> 4) + i * 16, nc = (t & 15) * 4;
        float4 v4 = *(const float4*)&W[(size_t)(k0 + kr) * CS + n0 + nc];
        ts[kr][nc] = v4.x; ts[kr][nc + 1] = v4.y;
        ts[kr][nc + 2] = v4.z; ts[kr][nc + 3] = v4.w;
    }
    __syncthreads();
    #pragma unroll
    for (int i = 0; i < 4; i++) {
        int nr = (t >> 4) + i * 16, kc = (t & 15) * 4;
        f16x4 h4;
        h4[0] = (f16)ts[kc][nr]; h4[1] = (f16)ts[kc + 1][nr];
        h4[2] = (f16)ts[kc + 2][nr]; h4[3] = (f16)ts[kc + 3][nr];
        *(f16x4*)&WT[(size_t)(n0 + nr) * CS + k0 + kc] = h4;
    }
}

// ---------------------------------------------------------------- k_gemm16
// C[2048 x 768] = A(f16 [m][k]) @ WT(f16 [n][k])^T, fp32 MFMA accumulate.
// BM=128 BN=128 BK=32; 4 waves (2x2), each wave owns a 64x64 tile: 16 MFMA
// per k-step vs 8 ds_reads. Fragment discipline (HW-verified in k_attn):
// A/B frag row via lane&15, k via (lane>>4)*8; C/D row=(lane>>4)*4+reg,
// col=lane&15.
// MODE 0: out = qkv buffer (b,h,s,d) fp32, z = blockIdx.z in {q,k,v}, fused
//         RMS over d (z<2): each 32-col half of the wave tile is one head.
// MODE 1: out[r*CS+c] = (acc + b_o[c]) * gate[b,c]  (fp32 d_out)
#define GP 40   // f16 LDS row pitch (80 B: 16B-aligned, 2-way banks = free)
template<int MODE>
__global__ __launch_bounds__(256) void k_gemm16(const f16* A, const f16* WT,
                                                float* out, const float* rwq,
                                                const float* rwk, const float* b_o,
                                                const float* emb) {
    __shared__ f16 As[128 * GP];
    __shared__ f16 Ws[128 * GP];
    int t = threadIdx.x;
    int m0 = blockIdx.x * 128, n0 = blockIdx.y * 128;
    int z = blockIdx.z;
    const f16* Ab = A + (size_t)m0 * CS;
    const f16* Wb = WT + (size_t)z * CS * CS + (size_t)n0 * CS;
    if (MODE == 0) out += (size_t)z * ((size_t)2 * SQ * CS);
    int w = t >> 6, l = t & 63;
    int lg = l >> 4, ll = l & 15;
    int wr = w >> 1, wc = w & 1;
    f32x4 acc[4][4] = {};
    for (int k0 = 0; k0 < CS; k0 += 32) {
        #pragma unroll
        for (int it = 0; it < 2; it++) {
            int seg = t + it * 256;              // 0..511
            int r = seg >> 2, cs8 = (seg & 3) * 8;
            *(f16x8*)&As[r * GP + cs8] = *(const f16x8*)&Ab[(size_t)r * CS + k0 + cs8];
            *(f16x8*)&Ws[r * GP + cs8] = *(const f16x8*)&Wb[(size_t)r * CS + k0 + cs8];
        }
        __syncthreads();
        f16x8 af[4], bf[4];
        #pragma unroll
        for (int mi = 0; mi < 4; mi++)
            af[mi] = *(const f16x8*)&As[(wr * 64 + mi * 16 + ll) * GP + lg * 8];
        #pragma unroll
        for (int ni = 0; ni < 4; ni++)
            bf[ni] = *(const f16x8*)&Ws[(wc * 64 + ni * 16 + ll) * GP + lg * 8];
        #pragma unroll
        for (int mi = 0; mi < 4; mi++)
            #pragma unroll
            for (int ni = 0; ni < 4; ni++)
                acc[mi][ni] = __builtin_amdgcn_mfma_f32_16x16x32_f16(
                    af[mi], bf[ni], acc[mi][ni], 0, 0, 0);
        __syncthreads();
    }
    int c0 = n0 + wc * 64;
    const float* rw = (z == 0) ? rwq : rwk;
    #pragma unroll
    for (int mi = 0; mi < 4; mi++) {
        #pragma unroll
        for (int rg = 0; rg < 4; rg++) {
            int r = m0 + wr * 64 + mi * 16 + lg * 4 + rg;
            int bb = r >> 10, s = r & 1023;
            if (MODE == 0) {
                #pragma unroll
                for (int pr = 0; pr < 2; pr++) {
                    float v0 = acc[mi][pr * 2][rg], v1 = acc[mi][pr * 2 + 1][rg];
                    if (z < 2) {   // fused RMS over the head's 32 d-values
                        float sq = v0 * v0 + v1 * v1;
                        sq += __shfl_xor(sq, 1); sq += __shfl_xor(sq, 2);
                        sq += __shfl_xor(sq, 4); sq += __shfl_xor(sq, 8);
                        float rsq = rsqrtf(sq * (1.0f / DD) + EPSV);
                        v0 *= rsq * rw[ll];
                        v1 *= rsq * rw[16 + ll];
                    }
                    int h = (c0 + pr * 32) >> 5;
                    float* op = out + (((size_t)bb * NH + h) * SQ + s) * DD;
                    op[ll] = v0;
                    op[16 + ll] = v1;
                }
            } else {
                const float* gt = emb + (size_t)bb * 3 * CS + 2 * CS;
                #pragma unroll
                for (int ni = 0; ni < 4; ni++) {
                    int col = c0 + ni * 16 + ll;
                    out[(size_t)r * CS + col] = (acc[mi][ni][rg] + b_o[col]) * gt[col];
                }
            }
        }
    }
}

// ---------------------------------------------------------------- k_uv
// U[h] = sum_c lnw[c]*wz[c,h];  V[h] = sum_c lnb[c]*wz[c,h]  (48 floats)
__global__ __launch_bounds__(64) void k_uv(const float* wz, const float* lnw,
                                           const float* lnb, float* uv) {
    int t = threadIdx.x;
    if (t < 2 * NH) {
        int h = t % NH;
        const float* s = (t < NH) ? lnw : lnb;
        float a = 0.f;
        for (int c = 0; c < CZ; ++c) a += s[c] * wz[c * NH + h];
        uv[t] = a;
    }
}

// ---------------------------------------------------------------- k_zbias
// zbias[h,i,j] = bf16( rs*P[h] - mu*rs*U[h] + V[h] + maskbias )
#define ZROWS 64
#define ZSTRIDE 132
__global__ __launch_bounds__(256) void k_zbias(const float* z, const int* zmask,
                                               const float* wz, const float* lnw,
                                               const float* lnb, const float* uv,
                                               bf16* zbias) {
    __shared__ float zt[ZROWS * ZSTRIDE];   // 33792 B; reused for partials
    __shared__ bf16 ot[NH][ZROWS];          // 3 KiB output staging
    int t = threadIdx.x;
    size_t base = (size_t)blockIdx.x * ZROWS;
    const float4* src = (const float4*)(z + base * CZ);
    // ---- stage 64x128, coalesced float4, swizzled LDS placement
    #pragma unroll
    for (int it = 0; it < 8; it++) {
        int gi = t + it * 256;                 // float4 index in 32 KiB chunk
        int row = gi >> 5, c4 = gi & 31;
        int cs = (c4 * 4) ^ ((row >> 3) << 2); // channel-group swizzle
        *(float4*)&zt[row * ZSTRIDE + cs] = src[gi];
    }
    __syncthreads();
    int lane = t & 63;
    int qd = __builtin_amdgcn_readfirstlane(t >> 6);   // wave id = channel quarter
    int sw = (lane >> 3) << 2;
    float acc[NH];
    #pragma unroll
    for (int h = 0; h < NH; h++) acc[h] = 0.f;
    float s1 = 0.f, s2 = 0.f;
    #pragma unroll
    for (int i = 0; i < 8; i++) {
        int c0 = qd * 32 + i * 4;              // wave-uniform channel base
        float4 zv = *(const float4*)&zt[lane * ZSTRIDE + (c0 ^ sw)];
        float e[4] = {zv.x, zv.y, zv.z, zv.w};
        #pragma unroll
        for (int u = 0; u < 4; u++) {
            int c = c0 + u;                    // wave-uniform -> s_loads below
            float zval = e[u];
            s1 += zval;
            s2 = fmaf(zval, zval, s2);
            float tc = zval * lnw[c];
            #pragma unroll
            for (int h = 0; h < NH; h++)
                acc[h] = fmaf(tc, wz[c * NH + h], acc[h]);
        }
    }
    __syncthreads();   // all waves done reading zt -> safe to reuse as partials
    {
        float* pp = zt + qd * (ZROWS * 27) + lane * 27;
        pp[0] = s1; pp[1] = s2;
        #pragma unroll
        for (int h = 0; h < NH; h++) pp[2 + h] = acc[h];
    }
    __syncthreads();
    int r = lane;
    int hb = qd * 6;
    float fs1 = 0.f, fs2 = 0.f;
    float fa[6] = {};
    #pragma unroll
    for (int q = 0; q < 4; q++) {
        const float* p = zt + q * (ZROWS * 27) + r * 27;
        fs1 += p[0]; fs2 += p[1];
        #pragma unroll
        for (int j = 0; j < 6; j++) fa[j] += p[2 + hb + j];
    }
    float mu = fs1 * (1.0f / CZ);
    float var = fs2 * (1.0f / CZ) - mu * mu;
    float rs = rsqrtf(var + EPSV);
    float mb = (zmask[base + r] > 0) ? 0.0f : -1.0e9f;
    #pragma unroll
    for (int j = 0; j < 6; j++) {
        int h = hb + j;
        float val = rs * fa[j] - mu * rs * uv[h] + uv[NH + h] + mb;
        ot[h][r] = f2b(val);
    }
    __syncthreads();
    size_t SS = (size_t)SQ * SQ;
    if (t < 192) {
        int h = t >> 3, l8 = t & 7;
        uint4 val = *(const uint4*)&ot[h][l8 * 8];
        *(uint4*)&zbias[(size_t)h * SS + base + l8 * 8] = val;
    }
}

// ---------------------------------------------------------------- k_attn
// flash attention per (b,h, 64-row q tile), f16 MFMA (16x16x32, K = D = 32).
// Defer-max (THR=8: P <= e^8 = 2981, f16-safe) kills the per-tile shfl max
// reduce in the common case; l kept as PER-LANE partials (each lane sums its
// 4 columns) and reduced across the 16-lane row group ONCE at the end.
#define PQK 40    // f16 pitch for Qs/Ks rows (80 B, 16B-aligned)
#define PPV 72    // f16 pitch for Ps/Vs rows (144 B, 16B-aligned)
__global__ __launch_bounds__(256) void k_attn(const float* q, const float* k,
                                              const float* v, const bf16* zbias,
                                              const float* beta, f16* attn_out) {
    int qt = blockIdx.x;   // 0..15
    int bh = blockIdx.y;   // 0..47
    int b = bh / NH, h = bh % NH;
    __shared__ f16 Qs[64 * PQK];   // [i][d] scaled
    __shared__ f16 Ks[64 * PQK];   // [j][d]
    __shared__ f16 Vs[32 * PPV];   // [d][j]  (transposed)
    __shared__ f16 Ps[64 * PPV];   // [i][j]
    int t = threadIdx.x;
    int w = t >> 6, l = t & 63;
    int lg = l >> 4, ll = l & 15;
    const float scale = 0.17677669529663687f;   // 1/sqrt(32)
    size_t SS = (size_t)SQ * SQ;
    int srow = t >> 2, sc0 = (t & 3) * 8;       // staging map: 8 f32 per thread

    // ---- stage Q once (scaled)
    {
        const float* qb = q + ((size_t)bh * SQ + qt * 64) * DD;
        float4 a0 = *(const float4*)&qb[srow * DD + sc0];
        float4 a1 = *(const float4*)&qb[srow * DD + sc0 + 4];
        f16x8 hv;
        hv[0] = (f16)(a0.x * scale); hv[1] = (f16)(a0.y * scale);
        hv[2] = (f16)(a0.z * scale); hv[3] = (f16)(a0.w * scale);
        hv[4] = (f16)(a1.x * scale); hv[5] = (f16)(a1.y * scale);
        hv[6] = (f16)(a1.z * scale); hv[7] = (f16)(a1.w * scale);
        *(f16x8*)&Qs[srow * PQK + sc0] = hv;
    }
    f32x4 accO0 = {0.f, 0.f, 0.f, 0.f}, accO1 = {0.f, 0.f, 0.f, 0.f};
    float m_reg[4], l_part[4];
    #pragma unroll
    for (int r = 0; r < 4; r++) { m_reg[r] = -3.0e38f; l_part[r] = 0.f; }

    // prefetch K/V tile 0 into regs
    float4 kr0, kr1, vr0, vr1;
    {
        const float* kb = k + ((size_t)bh * SQ) * DD;
        const float* vb = v + ((size_t)bh * SQ) * DD;
        kr0 = *(const float4*)&kb[srow * DD + sc0];
        kr1 = *(const float4*)&kb[srow * DD + sc0 + 4];
        vr0 = *(const float4*)&vb[srow * DD + sc0];
        vr1 = *(const float4*)&vb[srow * DD + sc0 + 4];
    }
    __syncthreads();   // Qs visible
    // write K/V tile 0 to LDS
    {
        f16x8 hk;
        hk[0] = (f16)kr0.x; hk[1] = (f16)kr0.y; hk[2] = (f16)kr0.z; hk[3] = (f16)kr0.w;
        hk[4] = (f16)kr1.x; hk[5] = (f16)kr1.y; hk[6] = (f16)kr1.z; hk[7] = (f16)kr1.w;
        *(f16x8*)&Ks[srow * PQK + sc0] = hk;
        float vv[8] = {vr0.x, vr0.y, vr0.z, vr0.w, vr1.x, vr1.y, vr1.z, vr1.w};
        #pragma unroll
        for (int u = 0; u < 8; u++) Vs[(sc0 + u) * PPV + srow] = (f16)vv[u];
    }
    const unsigned short* zb = (const unsigned short*)(zbias + (size_t)h * SS);
    const float* bb = beta + (size_t)b * SS;
    int ibase = qt * 64 + w * 16 + lg * 4;

    for (int kt = 0; kt < 16; kt++) {
        __syncthreads();   // staged tile visible
        if (kt < 15) {     // prefetch next tile (global -> regs, hides latency)
            const float* kb = k + ((size_t)bh * SQ + (kt + 1) * 64) * DD;
            const float* vb = v + ((size_t)bh * SQ + (kt + 1) * 64) * DD;
            kr0 = *(const float4*)&kb[srow * DD + sc0];
            kr1 = *(const float4*)&kb[srow * DD + sc0 + 4];
            vr0 = *(const float4*)&vb[srow * DD + sc0];
            vr1 = *(const float4*)&vb[srow * DD + sc0 + 4];
        }
        // ---- C-init = bias (zbias bf16 + beta f32), C layout row=(lg*4+r) col=ll
        f32x4 acc[4];
        #pragma unroll
        for (int c = 0; c < 4; c++) {
            #pragma unroll
            for (int r = 0; r < 4; r++) {
                size_t off = (size_t)(ibase + r) * SQ + kt * 64 + c * 16 + ll;
                union { unsigned u; float f; } cv;
                cv.u = (unsigned)zb[off] << 16;
                acc[c][r] = cv.f + bb[off];
            }
        }
        // ---- QK^T: one MFMA per 16x16 tile (K = 32 in one shot)
        f16x8 aQ = *(const f16x8*)&Qs[(w * 16 + ll) * PQK + lg * 8];
        #pragma unroll
        for (int c = 0; c < 4; c++) {
            f16x8 bK = *(const f16x8*)&Ks[(c * 16 + ll) * PQK + lg * 8];
            acc[c] = __builtin_amdgcn_mfma_f32_16x16x32_f16(aQ, bK, acc[c], 0, 0, 0);
        }
        // ---- online softmax with defer-max; l accumulated per-lane
        #pragma unroll
        for (int r = 0; r < 4; r++) {
            float lm = fmaxf(fmaxf(acc[0][r], acc[1][r]), fmaxf(acc[2][r], acc[3][r]));
            if (__any(lm > m_reg[r] + 8.0f)) {   // rare: raise m, rescale state
                float mx = lm;
                #pragma unroll
                for (int off = 1; off < 16; off <<= 1) mx = fmaxf(mx, __shfl_xor(mx, off, 64));
                float mn = fmaxf(m_reg[r], mx);
                float al = __expf(m_reg[r] - mn);
                m_reg[r] = mn;
                l_part[r] *= al;
                accO0[r] *= al;
                accO1[r] *= al;
            }
            float ps = 0.f;
            #pragma unroll
            for (int c = 0; c < 4; c++) {
                float p = __expf(acc[c][r] - m_reg[r]);
                acc[c][r] = p;
                ps += p;
            }
            l_part[r] += ps;    // lane-local; cross-lane reduce deferred to end
        }
        // ---- P -> f16 LDS (wave-private rows)
        #pragma unroll
        for (int c = 0; c < 4; c++)
            #pragma unroll
            for (int r = 0; r < 4; r++)
                Ps[(w * 16 + lg * 4 + r) * PPV + c * 16 + ll] = (f16)acc[c][r];
        // wave-internal: ensure P writes landed before cross-lane P reads
        __asm__ volatile("s_waitcnt lgkmcnt(0)" ::: "memory");
        // ---- PV: [64 rows x 32 d] += P[64x64] @ V[64x32]
        #pragma unroll
        for (int jt = 0; jt < 2; jt++) {
            f16x8 aP = *(const f16x8*)&Ps[(w * 16 + ll) * PPV + jt * 32 + lg * 8];
            f16x8 bV0 = *(const f16x8*)&Vs[(ll) * PPV + jt * 32 + lg * 8];
            f16x8 bV1 = *(const f16x8*)&Vs[(16 + ll) * PPV + jt * 32 + lg * 8];
            accO0 = __builtin_amdgcn_mfma_f32_16x16x32_f16(aP, bV0, accO0, 0, 0, 0);
            accO1 = __builtin_amdgcn_mfma_f32_16x16x32_f16(aP, bV1, accO1, 0, 0, 0);
        }
        __syncthreads();   // all waves done reading Ks/Vs
        if (kt < 15) {     // write next tile regs -> LDS
            f16x8 hk;
            hk[0] = (f16)kr0.x; hk[1] = (f16)kr0.y; hk[2] = (f16)kr0.z; hk[3] = (f16)kr0.w;
            hk[4] = (f16)kr1.x; hk[5] = (f16)kr1.y; hk[6] = (f16)kr1.z; hk[7] = (f16)kr1.w;
            *(f16x8*)&Ks[srow * PQK + sc0] = hk;
            float vv[8] = {vr0.x, vr0.y, vr0.z, vr0.w, vr1.x, vr1.y, vr1.z, vr1.w};
            #pragma unroll
            for (int u = 0; u < 8; u++) Vs[(sc0 + u) * PPV + srow] = (f16)vv[u];
        }
    }
    // ---- epilogue: combine per-lane l partials (once), normalize, store f16
    #pragma unroll
    for (int r = 0; r < 4; r++) {
        float lf = l_part[r];
        lf += __shfl_xor(lf, 1, 64); lf += __shfl_xor(lf, 2, 64);
        lf += __shfl_xor(lf, 4, 64); lf += __shfl_xor(lf, 8, 64);
        float inv = 1.0f / lf;
        int row = qt * 64 + w * 16 + lg * 4 + r;
        f16* op = attn_out + ((size_t)b * SQ + row) * CS + h * DD;
        op[ll] = (f16)(accO0[r] * inv);
        op[16 + ll] = (f16)(accO1[r] * inv);
    }
}

// ---------------------------------------------------------------- launch
extern "C" void kernel_launch(void* const* d_in, const int* in_sizes, int n_in,
                              void* d_out, int out_size, void* d_ws, size_t ws_size,
                              hipStream_t stream) {
    const float* bs      = (const float*)d_in[0];
    const float* z       = (const float*)d_in[1];
    const float* t       = (const float*)d_in[2];
    const float* beta    = (const float*)d_in[3];
    const int*   z_mask  = (const int*)d_in[4];
    const float* w_adaln = (const float*)d_in[5];
    const float* b_adaln = (const float*)d_in[6];
    const float* ln_z_w  = (const float*)d_in[7];
    const float* ln_z_b  = (const float*)d_in[8];
    const float* w_q     = (const float*)d_in[9];
    const float* w_k     = (const float*)d_in[10];
    const float* w_v     = (const float*)d_in[11];
    const float* w_z     = (const float*)d_in[12];
    const float* rms_q_w = (const float*)d_in[13];
    const float* rms_k_w = (const float*)d_in[14];
    const float* w_o     = (const float*)d_in[15];
    const float* b_o     = (const float*)d_in[16];
    float* out = (float*)d_out;

    char* ws = (char*)d_ws;
    const size_t SZ_QKV = (size_t)2 * SQ * CS * 4;   // 6291456 (fp32 qkv slot)
    float* emb   = (float*)(ws);                      // 2*2304*4 = 18432
    f16*   bsn   = (f16*)(ws + 32768);                // f16 2048x768 (slot reused)
    float* qbuf  = (float*)(ws + 32768 + SZ_QKV);     // q,k,v contiguous fp32
    float* kbuf  = (float*)(ws + 32768 + 2 * SZ_QKV);
    float* vbuf  = (float*)(ws + 32768 + 3 * SZ_QKV);
    f16*   attn  = (f16*)(ws + 32768 + 4 * SZ_QKV);   // f16 2048x768
    bf16*  zbias = (bf16*)(ws + 32768 + 5 * SZ_QKV);  // 24*1024*1024*2 = 50331648
    float* uv    = (float*)(ws + 32768 + 5 * SZ_QKV + 50331648);  // 48 floats
    f16*   wt    = (f16*)(ws + 32768 + 5 * SZ_QKV + 50331648 + 4096); // 4x768x768 f16

    k_adaln<<<dim3(9, 2), 256, 0, stream>>>(t, w_adaln, b_adaln, emb);
    k_uv<<<1, 64, 0, stream>>>(w_z, ln_z_w, ln_z_b, uv);
    k_wt<<<dim3(12, 12, 4), 256, 0, stream>>>(w_q, w_k, w_v, w_o, wt);
    k_bsnorm<<<2048, 256, 0, stream>>>(bs, emb, bsn);
    k_gemm16<0><<<dim3(16, 6, 3), 256, 0, stream>>>(bsn, wt, qbuf, rms_q_w,
                                                    rms_k_w, nullptr, nullptr);
    k_zbias<<<16384, 256, 0, stream>>>(z, z_mask, w_z, ln_z_w, ln_z_b, uv, zbias);
    k_attn<<<dim3(16, 48), 256, 0, stream>>>(qbuf, kbuf, vbuf, zbias, beta, attn);
    k_gemm16<1><<<dim3(16, 6, 1), 256, 0, stream>>>(attn, wt + (size_t)3 * CS * CS,
                                                    out, nullptr, nullptr, b_o, emb);
}